// Round 14
// baseline (320.899 us; speedup 1.0000x reference)
//
#include <hip/hip_runtime.h>
#include <hip/hip_bf16.h>

typedef __bf16 bf16;
typedef __bf16 bf16x8 __attribute__((ext_vector_type(8)));
typedef __bf16 bf16x4 __attribute__((ext_vector_type(4)));
typedef float f32x4 __attribute__((ext_vector_type(4)));

#define B_    2
#define S_    2048
#define HD    2048
#define NH    16
#define DQK   192
#define DV    128
#define QR    1536
#define KVR   512
#define NTOK  4096
#define NKVB  4096   /* N_HEADS*(D_NOPE+D_V) */
#define NQB   3072   /* N_HEADS*D_QK */
#define NQKVA 2176   /* QR + 640 (padded kv_a) */

#define EXP2F(x) __builtin_amdgcn_exp2f(x)

static __device__ __forceinline__ void gload16(const void* g, void* l) {
  __builtin_amdgcn_global_load_lds(
      (const __attribute__((address_space(1))) void*)g,
      (__attribute__((address_space(3))) void*)l, 16, 0, 0);
}

// ---------------- f32 -> bf16 convert ----------------
__global__ __launch_bounds__(256) void cvt_bf16(const float* __restrict__ in,
                                                bf16* __restrict__ out, long n) {
  long i = ((long)blockIdx.x * 256 + threadIdx.x) * 4;
  if (i + 3 < n) {
    float4 v = *(const float4*)(in + i);
    bf16x4 o = {(bf16)v.x, (bf16)v.y, (bf16)v.z, (bf16)v.w};
    *(bf16x4*)(out + i) = o;
  }
}

// ---------------- merged weight transposes: 5 segments, one launch ------------
struct TransArgs {
  const float *s0, *s1, *s2, *s3, *s4;
  bf16 *d0, *d1, *d2, *d3, *d4;
};
__global__ __launch_bounds__(256) void transpose_all(TransArgs a) {
  __shared__ float tile[32][33];
  int bid = blockIdx.x;
  int seg, rel;
  if      (bid < 3072)  { seg = 0; rel = bid; }
  else if (bid < 4352)  { seg = 1; rel = bid - 3072; }
  else if (bid < 8960)  { seg = 2; rel = bid - 4352; }
  else if (bid < 11008) { seg = 3; rel = bid - 8960; }
  else                  { seg = 4; rel = bid - 11008; }
  const float* in = seg == 0 ? a.s0 : seg == 1 ? a.s1 : seg == 2 ? a.s2 : seg == 3 ? a.s3 : a.s4;
  bf16* out       = seg == 0 ? a.d0 : seg == 1 ? a.d1 : seg == 2 ? a.d2 : seg == 3 ? a.d3 : a.d4;
  int R   = seg == 0 ? 2048 : seg == 1 ? 2048 : seg == 2 ? 1536 : seg == 3 ? 512 : 2048;
  int C   = seg == 0 ? 1536 : seg == 1 ? 576  : seg == 2 ? 3072 : seg == 3 ? 4096 : 2048;
  int Np  = seg == 0 ? 1536 : seg == 1 ? 640  : seg == 2 ? 3072 : seg == 3 ? 4096 : 2048;
  int nbx = seg == 0 ? 48   : seg == 1 ? 20   : seg == 2 ? 96   : seg == 3 ? 128 : 64;
  int c0 = (rel % nbx) * 32;
  int r0 = (rel / nbx) * 32;
  int tx = threadIdx.x & 31, ty = threadIdx.x >> 5;
#pragma unroll
  for (int i = 0; i < 4; ++i) {
    int r = r0 + ty + i * 8, c = c0 + tx;
    tile[ty + i * 8][tx] = (c < C) ? in[(long)r * C + c] : 0.f;
  }
  __syncthreads();
#pragma unroll
  for (int i = 0; i < 4; ++i) {
    int oc = c0 + ty + i * 8;
    if (oc < Np) out[(long)oc * R + r0 + tx] = (bf16)tile[tx][ty + i * 8];
  }
}

// ============ shared GEMM core: 128x128 tile, BK=64, XOR chunk swizzle ========
#define GEMM_CORE(A, Bt, K)                                                    \
  __shared__ bf16 As[128 * 64];                                                \
  __shared__ bf16 Bs[128 * 64];                                                \
  const int t = threadIdx.x;                                                   \
  const int l = t & 63;                                                        \
  const int w = t >> 6;                                                        \
  const int m0 = blockIdx.y * 128;                                             \
  const int n0 = blockIdx.x * 128;                                             \
  const int wr = (w >> 1) * 64;                                                \
  const int wc = (w & 1) * 64;                                                 \
  const int lr = l & 15;                                                       \
  const int lg = l >> 4;                                                       \
  f32x4 acc[4][4] = {};                                                        \
  for (int k0 = 0; k0 < (K); k0 += 64) {                                       \
    __syncthreads();                                                           \
    _Pragma("unroll")                                                          \
    for (int j = 0; j < 4; ++j) {                                              \
      int s = j * 256 + t;                                                     \
      int row = s >> 3, sc = s & 7;                                            \
      int c = sc ^ (row & 7);                                                  \
      gload16((A) + (long)(m0 + row) * (K) + k0 + c * 8,                       \
              As + (j * 256 + w * 64) * 8);                                    \
      gload16((Bt) + (long)(n0 + row) * (K) + k0 + c * 8,                      \
              Bs + (j * 256 + w * 64) * 8);                                    \
    }                                                                          \
    __syncthreads();                                                           \
    _Pragma("unroll")                                                          \
    for (int kh = 0; kh < 2; ++kh) {                                           \
      bf16x8 af[4], bfr[4];                                                    \
      _Pragma("unroll")                                                        \
      for (int m = 0; m < 4; ++m) {                                            \
        int row = wr + m * 16 + lr;                                            \
        af[m] = *(const bf16x8*)(As + row * 64 + (((kh * 4 + lg) ^ (row & 7)) << 3)); \
      }                                                                        \
      _Pragma("unroll")                                                        \
      for (int n = 0; n < 4; ++n) {                                            \
        int row = wc + n * 16 + lr;                                            \
        bfr[n] = *(const bf16x8*)(Bs + row * 64 + (((kh * 4 + lg) ^ (row & 7)) << 3)); \
      }                                                                        \
      _Pragma("unroll")                                                        \
      for (int m = 0; m < 4; ++m)                                              \
        _Pragma("unroll")                                                      \
        for (int n = 0; n < 4; ++n)                                            \
          acc[m][n] = __builtin_amdgcn_mfma_f32_16x16x32_bf16(af[m], bfr[n], acc[m][n], 0, 0, 0); \
    }                                                                          \
  }

// ---------------- generic GEMM: C[M][N] = A @ Bt^T ----------------------------
template <typename CT>
__global__ __launch_bounds__(256) void gemm_bf16(const bf16* __restrict__ A,
                                                 const bf16* __restrict__ Bt,
                                                 CT* __restrict__ C,
                                                 int M, int N, int K) {
  GEMM_CORE(A, Bt, K)
#pragma unroll
  for (int m = 0; m < 4; ++m)
#pragma unroll
    for (int n = 0; n < 4; ++n)
#pragma unroll
      for (int v = 0; v < 4; ++v) {
        int row = m0 + wr + m * 16 + lg * 4 + v;
        int col = n0 + wc + n * 16 + lr;
        C[(long)row * N + col] = (CT)acc[m][n][v];
      }
}

// ============ gemm8p core: 256x256 tile, BK=64, 8 waves, 2-dbuf, counted vmcnt
#define G8P_CORE(A, Bt, K)                                                     \
  __shared__ bf16 As_[2][256 * 64];                                            \
  __shared__ bf16 Bs_[2][256 * 64];                                            \
  const int t = threadIdx.x;                                                   \
  const int w = t >> 6, l = t & 63;                                            \
  const int lr = l & 15, lg = l >> 4;                                          \
  const int wm = w >> 2, wn = w & 3;                                           \
  const int m0 = blockIdx.y * 256, n0 = blockIdx.x * 256;                      \
  const int NT = (K) >> 6;                                                     \
  const int tr = t >> 3, sc = t & 7;                                           \
  f32x4 acc[8][4] = {};                                                        \
  auto stg = [&](int kt, int j) {                                              \
    int jj = j & 3;                                                            \
    int row = jj * 64 + tr;                                                    \
    int c = sc ^ (row & 7);                                                    \
    const bf16* src = (j < 4)                                                  \
        ? (A)  + (long)(m0 + row) * (K) + kt * 64 + c * 8                      \
        : (Bt) + (long)(n0 + row) * (K) + kt * 64 + c * 8;                     \
    bf16* dst = ((j < 4) ? As_[kt & 1] : Bs_[kt & 1]) + (jj * 512 + w * 64) * 8; \
    gload16(src, dst);                                                         \
  };                                                                           \
  _Pragma("unroll") for (int j = 0; j < 8; ++j) stg(0, j);                     \
  _Pragma("unroll") for (int j = 0; j < 8; ++j) stg(1, j);                     \
  for (int kt = 0; kt < NT; ++kt) {                                            \
    const bf16* Ab = As_[kt & 1];                                              \
    const bf16* Bb = Bs_[kt & 1];                                              \
    if (kt == NT - 1) { asm volatile("s_waitcnt vmcnt(0)" ::: "memory"); }     \
    else              { asm volatile("s_waitcnt vmcnt(8)" ::: "memory"); }     \
    __builtin_amdgcn_s_barrier();                                              \
    asm volatile("" ::: "memory");                                             \
    bf16x8 af[8][2], bfr[4][2];                                                \
    _Pragma("unroll")                                                          \
    for (int mi = 0; mi < 8; ++mi) {                                           \
      int row = wm * 128 + mi * 16 + lr;                                       \
      _Pragma("unroll")                                                        \
      for (int kh = 0; kh < 2; ++kh)                                           \
        af[mi][kh] = *(const bf16x8*)(Ab + row * 64 + (((kh * 4 + lg) ^ (row & 7)) << 3)); \
    }                                                                          \
    _Pragma("unroll")                                                          \
    for (int ni = 0; ni < 4; ++ni) {                                           \
      int row = wn * 64 + ni * 16 + lr;                                        \
      _Pragma("unroll")                                                        \
      for (int kh = 0; kh < 2; ++kh)                                           \
        bfr[ni][kh] = *(const bf16x8*)(Bb + row * 64 + (((kh * 4 + lg) ^ (row & 7)) << 3)); \
    }                                                                          \
    asm volatile("s_waitcnt lgkmcnt(0)" ::: "memory");                         \
    __builtin_amdgcn_sched_barrier(0);                                         \
    __builtin_amdgcn_s_setprio(1);                                             \
    _Pragma("unroll")                                                          \
    for (int mi = 0; mi < 8; ++mi)                                             \
      _Pragma("unroll")                                                        \
      for (int kh = 0; kh < 2; ++kh)                                           \
        acc[mi][0] = __builtin_amdgcn_mfma_f32_16x16x32_bf16(af[mi][kh], bfr[0][kh], acc[mi][0], 0, 0, 0); \
    __builtin_amdgcn_s_setprio(0);                                             \
    __builtin_amdgcn_s_barrier();  /* all waves' ds_reads done: dbufs free */  \
    asm volatile("" ::: "memory");                                             \
    bool more = (kt + 2) < NT;                                                 \
    if (more) { stg(kt + 2, 0); stg(kt + 2, 1); stg(kt + 2, 2); }              \
    __builtin_amdgcn_s_setprio(1);                                             \
    _Pragma("unroll")                                                          \
    for (int mi = 0; mi < 8; ++mi)                                             \
      _Pragma("unroll")                                                        \
      for (int kh = 0; kh < 2; ++kh)                                           \
        acc[mi][1] = __builtin_amdgcn_mfma_f32_16x16x32_bf16(af[mi][kh], bfr[1][kh], acc[mi][1], 0, 0, 0); \
    __builtin_amdgcn_s_setprio(0);                                             \
    if (more) { stg(kt + 2, 3); stg(kt + 2, 4); stg(kt + 2, 5); }              \
    __builtin_amdgcn_s_setprio(1);                                             \
    _Pragma("unroll")                                                          \
    for (int mi = 0; mi < 8; ++mi)                                             \
      _Pragma("unroll")                                                        \
      for (int kh = 0; kh < 2; ++kh)                                           \
        acc[mi][2] = __builtin_amdgcn_mfma_f32_16x16x32_bf16(af[mi][kh], bfr[2][kh], acc[mi][2], 0, 0, 0); \
    __builtin_amdgcn_s_setprio(0);                                             \
    if (more) { stg(kt + 2, 6); stg(kt + 2, 7); }                              \
    __builtin_amdgcn_s_setprio(1);                                             \
    _Pragma("unroll")                                                          \
    for (int mi = 0; mi < 8; ++mi)                                             \
      _Pragma("unroll")                                                        \
      for (int kh = 0; kh < 2; ++kh)                                           \
        acc[mi][3] = __builtin_amdgcn_mfma_f32_16x16x32_bf16(af[mi][kh], bfr[3][kh], acc[mi][3], 0, 0, 0); \
    __builtin_amdgcn_s_setprio(0);                                             \
  }

// ---------------- gemm8p fused q_f: RoPE + SCALE*LOG2E -> q_bhsd --------------
__global__ __launch_bounds__(512) void gemm8p_qf(const bf16* __restrict__ A,
                                                 const bf16* __restrict__ Bt,
                                                 const int* __restrict__ pos,
                                                 const float* __restrict__ cosT,
                                                 const float* __restrict__ sinT,
                                                 bf16* __restrict__ q_bhsd) {
  const float SCALE = 0.07216878364870323f * 1.4426950408889634f;
  G8P_CORE(A, Bt, QR)
  int c0 = n0 + wn * 64;
  int h = c0 / 192;
  int part = c0 - h * 192;            // 0, 64, or 128 (wave-uniform)
#pragma unroll
  for (int mi = 0; mi < 8; ++mi)
#pragma unroll
    for (int v = 0; v < 4; ++v) {
      int row = m0 + wm * 128 + mi * 16 + lg * 4 + v;
      int b = row >> 11, s = row & (S_ - 1);
      long base = ((long)(b * NH + h) * S_ + s) * DQK;
      if (part < 128) {
#pragma unroll
        for (int ni = 0; ni < 4; ++ni)
          q_bhsd[base + part + ni * 16 + lr] = (bf16)(acc[mi][ni][v] * SCALE);
      } else {
        int p = pos[s] & (S_ - 1);
        float c_lo = cosT[p * 32 + lr],      s_lo = sinT[p * 32 + lr];
        float c_hi = cosT[p * 32 + 16 + lr], s_hi = sinT[p * 32 + 16 + lr];
        float o0 = acc[mi][0][v] * c_lo - acc[mi][2][v] * s_lo;
        float o1 = acc[mi][1][v] * c_hi - acc[mi][3][v] * s_hi;
        float o2 = acc[mi][0][v] * s_lo + acc[mi][2][v] * c_lo;
        float o3 = acc[mi][1][v] * s_hi + acc[mi][3][v] * c_hi;
        q_bhsd[base + 128 + lr] = (bf16)(o0 * SCALE);
        q_bhsd[base + 144 + lr] = (bf16)(o1 * SCALE);
        q_bhsd[base + 160 + lr] = (bf16)(o2 * SCALE);
        q_bhsd[base + 176 + lr] = (bf16)(o3 * SCALE);
      }
    }
}

// ---------------- gemm8p fused kv_b: k -> k_bhsd, v -> v_t (direct transpose) -
__global__ __launch_bounds__(512) void gemm8p_kvb(const bf16* __restrict__ A,
                                                  const bf16* __restrict__ Bt,
                                                  bf16* __restrict__ k_bhsd,
                                                  bf16* __restrict__ v_t) {
  G8P_CORE(A, Bt, KVR)
  int c0 = n0 + wn * 64;
  int h = c0 >> 8;
  int dbase = c0 & 64;
  bool vpart = (c0 >> 7) & 1;
  if (!vpart) {
#pragma unroll
    for (int mi = 0; mi < 8; ++mi)
#pragma unroll
      for (int v = 0; v < 4; ++v) {
        int row = m0 + wm * 128 + mi * 16 + lg * 4 + v;
        int b = row >> 11, s = row & (S_ - 1);
        long base = ((long)(b * NH + h) * S_ + s) * DQK + dbase;
#pragma unroll
        for (int ni = 0; ni < 4; ++ni)
          k_bhsd[base + ni * 16 + lr] = (bf16)acc[mi][ni][v];
      }
  } else {
#pragma unroll
    for (int mi = 0; mi < 8; ++mi) {
      int row0 = m0 + wm * 128 + mi * 16 + lg * 4;
      int b = row0 >> 11, s = row0 & (S_ - 1);
#pragma unroll
      for (int ni = 0; ni < 4; ++ni) {
        int d = dbase + ni * 16 + lr;
        bf16x4 o = {(bf16)acc[mi][ni][0], (bf16)acc[mi][ni][1],
                    (bf16)acc[mi][ni][2], (bf16)acc[mi][ni][3]};
        *(bf16x4*)(v_t + ((long)(b * NH + h) * DV + d) * S_ + s) = o;
      }
    }
  }
}

// ---------------- merged norm+prep: waves 0-2 q-RMSNorm, wave 3 kv+rope -------
__global__ __launch_bounds__(256) void norm_prep(const bf16* __restrict__ xa,   // [NTOK][2176]
                                                 const float* __restrict__ g_qa,
                                                 const float* __restrict__ g_kva,
                                                 const int* __restrict__ pos,
                                                 const float* __restrict__ cosT,
                                                 const float* __restrict__ sinT,
                                                 bf16* __restrict__ q_n,       // [NTOK][1536]
                                                 bf16* __restrict__ kv_l,      // [NTOK][512]
                                                 bf16* __restrict__ k_bhsd) {  // [B][H][S][192]
  int row = blockIdx.x;
  int t = threadIdx.x;
  int b = row >> 11, s = row & (S_ - 1);
  const bf16* xr = xa + (long)row * NQKVA;
  __shared__ float red[3];
  __shared__ bf16 rope_s[64];
  float vf[8];
  if (t < 192) {
    bf16x8 vv = *(const bf16x8*)(xr + t * 8);
    float ss = 0.f;
#pragma unroll
    for (int e = 0; e < 8; ++e) { vf[e] = (float)vv[e]; ss += vf[e] * vf[e]; }
#pragma unroll
    for (int m = 1; m < 64; m <<= 1) ss += __shfl_xor(ss, m);
    if ((t & 63) == 0) red[t >> 6] = ss;
  } else {
    int tt = t - 192;
    const bf16* xl = xr + QR;
    bf16x8 vv = *(const bf16x8*)(xl + tt * 8);
    float ss = 0.f;
#pragma unroll
    for (int e = 0; e < 8; ++e) { vf[e] = (float)vv[e]; ss += vf[e] * vf[e]; }
#pragma unroll
    for (int m = 1; m < 64; m <<= 1) ss += __shfl_xor(ss, m);
    float rs = rsqrtf(ss / KVR + 1e-5f);
    bf16x8 o;
#pragma unroll
    for (int e = 0; e < 8; ++e) o[e] = (bf16)(vf[e] * rs * g_kva[tt * 8 + e]);
    *(bf16x8*)(kv_l + (long)row * KVR + tt * 8) = o;
    if (tt < 32) {
      int p = pos[s] & (S_ - 1);
      float c = cosT[p * 32 + tt], sn = sinT[p * 32 + tt];
      float x0 = (float)xl[512 + tt], x1 = (float)xl[544 + tt];
      rope_s[tt] = (bf16)(x0 * c - x1 * sn);
      rope_s[32 + tt] = (bf16)(x0 * sn + x1 * c);
    }
  }
  __syncthreads();
  if (t < 192) {
    float ss = red[0] + red[1] + red[2];
    float rs = rsqrtf(ss / QR + 1e-5f);
    bf16x8 o;
#pragma unroll
    for (int e = 0; e < 8; ++e) o[e] = (bf16)(vf[e] * rs * g_qa[t * 8 + e]);
    *(bf16x8*)(q_n + (long)row * QR + t * 8) = o;
  } else {
    int tt = t - 192;
    bf16x8 rv = *(const bf16x8*)&rope_s[(tt & 7) * 8];
    long base0 = ((long)(b * NH + (tt >> 3)) * S_ + s) * DQK + 128 + (tt & 7) * 8;
    long base1 = ((long)(b * NH + 8 + (tt >> 3)) * S_ + s) * DQK + 128 + (tt & 7) * 8;
    *(bf16x8*)(k_bhsd + base0) = rv;
    *(bf16x8*)(k_bhsd + base1) = rv;
  }
}

// ---------------- flash v6: 4 waves x 32 q-rows -> 2x fragment reuse ----------
// LDS-BW fix: each K-frag feeds 2 MFMAs (rg=0,1), each V-frag feeds 2.
// Per tile/wave: 84 MFMA / 46 LDS reads (flash4: 42/44). Single-buffered
// (dbuf proven null), V in LDS, ones-row l, defer-max, exp2. LDS 60 KB.
#define KVB  64
#define DVP  144
__global__ __launch_bounds__(256) void flash6(const bf16* __restrict__ q_bhsd,
                                              const bf16* __restrict__ k_bhsd,
                                              const bf16* __restrict__ v_t,
                                              bf16* __restrict__ att) {  // [NTOK][2048]
  __shared__ bf16 Ks[KVB * DQK];      // 24 KB, swizzled 16B chunks
  __shared__ bf16 Vs[DVP * KVB];      // 18 KB, rows 0-127 staged, 128-143 const
  __shared__ bf16 Ps[4][32 * 72];     // 18 KB, per-wave P (32 rows), padded 72
  int bid = blockIdx.x;
  int bh = bid & 31;                  // head-of-batch: fixes XCD = bh%8
  int qt = 15 - (bid >> 5);           // heaviest (most k-tiles) first
  int b = bh >> 4, h = bh & 15;
  int q0 = qt * 128;
  int t = threadIdx.x;
  int w = t >> 6, l = t & 63;
  int lr = l & 15, lg = l >> 4;
  int qw = q0 + w * 32;               // this wave's first q row (32 rows)
  const int lr7 = lr & 7;

  const bf16* Qb = q_bhsd + (long)bh * S_ * DQK;
  const bf16* Kb = k_bhsd + (long)bh * S_ * DQK;
  const bf16* Vb = v_t + (long)bh * DV * S_;

  // init ones/zero rows of Vs (persist across tiles; staging never touches them)
  if (t < 128) {
    int rr = 128 + (t >> 3), cc = (t & 7) * 8;
    bf16 val = (bf16)((rr == 128) ? 1.0f : 0.0f);
    bf16x8 vvv = {val, val, val, val, val, val, val, val};
    *(bf16x8*)(Vs + rr * KVB + cc) = vvv;
  }

  bf16x8 qf[2][6];
#pragma unroll
  for (int rg = 0; rg < 2; ++rg)
#pragma unroll
    for (int t6 = 0; t6 < 6; ++t6)
      qf[rg][t6] = *(const bf16x8*)(Qb + (long)(qw + rg * 16 + lr) * DQK + t6 * 32 + lg * 8);

  f32x4 oacc[2][9] = {};              // [rg][0..7] output, [rg][8] = l
  float mrow[2][4] = {{-1e30f,-1e30f,-1e30f,-1e30f},{-1e30f,-1e30f,-1e30f,-1e30f}};

  int nkt = 2 * qt + 2;
  for (int kt = 0; kt < nkt; ++kt) {
    int k0 = kt * KVB;
    __syncthreads();
    // stage K: 1536 chunks (6 x 256); slot s holds global chunk (r, c^(r&7))
#pragma unroll
    for (int j = 0; j < 6; ++j) {
      int s = j * 256 + t;
      int r = s / 24, c1 = s - r * 24;
      int c = c1 ^ (r & 7);
      gload16(Kb + (long)(k0 + r) * DQK + c * 8, Ks + (j * 256 + w * 64) * 8);
    }
    // stage V: 1024 chunks (4 x 256), rows 0..127 only
#pragma unroll
    for (int j = 0; j < 4; ++j) {
      int s = j * 256 + t;
      int d = s >> 3, c1 = s & 7;
      int c = c1 ^ (d & 7);
      gload16(Vb + (long)d * S_ + k0 + c * 8, Vs + (j * 256 + w * 64) * 8);
    }
    __syncthreads();
    if (k0 > qw + 31) continue;       // fully masked for this wave

    // ---- QK^T: sacc[rg][n] = scores[q=qw+rg*16+lg*4+v][k=n*16+lr] ----
    f32x4 sacc[2][4] = {};
#pragma unroll
    for (int n = 0; n < 4; ++n) {
      int rk = n * 16 + lr;
#pragma unroll
      for (int t6 = 0; t6 < 6; ++t6) {
        bf16x8 kf = *(const bf16x8*)(Ks + rk * DQK + (((t6 * 4 + lg) ^ lr7) << 3));
        sacc[0][n] = __builtin_amdgcn_mfma_f32_16x16x32_bf16(qf[0][t6], kf, sacc[0][n], 0, 0, 0);
        sacc[1][n] = __builtin_amdgcn_mfma_f32_16x16x32_bf16(qf[1][t6], kf, sacc[1][n], 0, 0, 0);
      }
    }
    // ---- causal mask (diagonal region only) ----
    if (k0 + KVB - 1 > qw) {
#pragma unroll
      for (int rg = 0; rg < 2; ++rg)
#pragma unroll
        for (int n = 0; n < 4; ++n)
#pragma unroll
          for (int v = 0; v < 4; ++v) {
            int r = rg * 16 + lg * 4 + v, c = n * 16 + lr;
            if (k0 + c > qw + r) sacc[rg][n][v] = -1e30f;
          }
    }
    // ---- tile row-max per rg ----
    float mv[2][4];
#pragma unroll
    for (int rg = 0; rg < 2; ++rg)
#pragma unroll
      for (int v = 0; v < 4; ++v) {
        mv[rg][v] = fmaxf(fmaxf(sacc[rg][0][v], sacc[rg][1][v]),
                          fmaxf(sacc[rg][2][v], sacc[rg][3][v]));
#pragma unroll
        for (int msk = 1; msk < 16; msk <<= 1)
          mv[rg][v] = fmaxf(mv[rg][v], __shfl_xor(mv[rg][v], msk));
      }
    // ---- defer-max: rescale only if some row max grew by > 8 (log2) ----
    bool grow = false;
#pragma unroll
    for (int rg = 0; rg < 2; ++rg)
#pragma unroll
      for (int v = 0; v < 4; ++v) grow |= (mv[rg][v] > mrow[rg][v] + 8.f);
    if (__any(grow)) {
#pragma unroll
      for (int rg = 0; rg < 2; ++rg) {
        float corr[4];
#pragma unroll
        for (int v = 0; v < 4; ++v) {
          float mt = fmaxf(mrow[rg][v], mv[rg][v]);
          corr[v] = EXP2F(mrow[rg][v] - mt);
          mrow[rg][v] = mt;
        }
#pragma unroll
        for (int dn = 0; dn < 9; ++dn)
#pragma unroll
          for (int v = 0; v < 4; ++v) oacc[rg][dn][v] *= corr[v];
      }
    }
    // ---- P = exp2(s - mrow); P -> LDS (per-wave, 32 rows, padded) ----
#pragma unroll
    for (int rg = 0; rg < 2; ++rg)
#pragma unroll
      for (int v = 0; v < 4; ++v)
#pragma unroll
        for (int n = 0; n < 4; ++n)
          Ps[w][(rg * 16 + lg * 4 + v) * 72 + n * 16 + lr] =
              (bf16)EXP2F(sacc[rg][n][v] - mrow[rg][v]);
    // ---- PV: each vf feeds both rgs; dn=8 hits the ones-rows => l ----
#pragma unroll
    for (int kc = 0; kc < 2; ++kc) {
      bf16x8 pf0 = *(const bf16x8*)(Ps[w] + lr * 72 + kc * 32 + lg * 8);
      bf16x8 pf1 = *(const bf16x8*)(Ps[w] + (16 + lr) * 72 + kc * 32 + lg * 8);
#pragma unroll
      for (int dn = 0; dn < 9; ++dn) {
        int d = dn * 16 + lr;
        bf16x8 vf = *(const bf16x8*)(Vs + d * KVB + (((kc * 4 + lg) ^ lr7) << 3));
        oacc[0][dn] = __builtin_amdgcn_mfma_f32_16x16x32_bf16(pf0, vf, oacc[0][dn], 0, 0, 0);
        oacc[1][dn] = __builtin_amdgcn_mfma_f32_16x16x32_bf16(pf1, vf, oacc[1][dn], 0, 0, 0);
      }
    }
  }
  // ---- epilogue: l in column d=128 (lanes lr==0); broadcast + divide ----
#pragma unroll
  for (int rg = 0; rg < 2; ++rg) {
    float rl[4];
#pragma unroll
    for (int v = 0; v < 4; ++v) {
      float lv = __shfl(oacc[rg][8][v], lg * 16);
      rl[v] = 1.0f / lv;
    }
#pragma unroll
    for (int dn = 0; dn < 8; ++dn)
#pragma unroll
      for (int v = 0; v < 4; ++v) {
        int r = rg * 16 + lg * 4 + v;
        float o = oacc[rg][dn][v] * rl[v];
        att[((long)(b * S_ + qw + r)) * 2048 + h * 128 + dn * 16 + lr] = (bf16)o;
      }
  }
}

extern "C" void kernel_launch(void* const* d_in, const int* in_sizes, int n_in,
                              void* d_out, int out_size, void* d_ws, size_t ws_size,
                              hipStream_t stream) {
  const float* x        = (const float*)d_in[0];
  const int* pos        = (const int*)d_in[1];   // harness passes integers as int32
  const float* Wqa      = (const float*)d_in[2];
  const float* g_qa     = (const float*)d_in[3];
  const float* Wqb      = (const float*)d_in[4];
  const float* Wkva     = (const float*)d_in[5];
  const float* g_kva    = (const float*)d_in[6];
  const float* Wkvb     = (const float*)d_in[7];
  const float* Wo       = (const float*)d_in[8];
  const float* cosT     = (const float*)d_in[9];
  const float* sinT     = (const float*)d_in[10];
  float* out            = (float*)d_out;

  // ---- workspace layout ----
  size_t off = 0;
  char* wsp = (char*)d_ws;
  auto alloc = [&](size_t n) { void* p = wsp + off; off += (n + 255) & ~(size_t)255; return p; };
  bf16*  Wqa_t  = (bf16*) alloc((size_t)QR * HD * 2);      // contiguous with
  bf16*  Wkva_t = (bf16*) alloc((size_t)640 * HD * 2);     //  ... Wqa_t (concat Bt)
  bf16*  Wqb_t  = (bf16*) alloc((size_t)NQB * QR * 2);
  bf16*  Wkvb_t = (bf16*) alloc((size_t)NKVB * KVR * 2);
  bf16*  Wo_t   = (bf16*) alloc((size_t)HD * HD * 2);
  bf16*  x_bf   = (bf16*) alloc((size_t)NTOK * HD * 2);
  bf16*  q_bhsd = (bf16*) alloc((size_t)B_ * NH * S_ * DQK * 2);
  bf16*  k_bhsd = (bf16*) alloc((size_t)B_ * NH * S_ * DQK * 2);
  bf16*  v_t    = (bf16*) alloc((size_t)B_ * NH * DV * S_ * 2);
  bf16*  att    = (bf16*) alloc((size_t)NTOK * 2048 * 2);
  char*  T      = (char*) alloc((size_t)33554432);         // 32 MB transient
  bf16*  xa  = (bf16*)T;                        // [NTOK][2176] = 17.8 MB
  bf16*  q_n = (bf16*)(T + 18874368);           // [NTOK][1536] = 12.6 MB
  bf16*  kv_l = (bf16*)(T + 18874368 + 12582912); // [NTOK][512] = 4.2 MB
  if (ws_size < off) return;

  cvt_bf16<<<(NTOK * HD / 4 + 255) / 256, 256, 0, stream>>>(x, x_bf, (long)NTOK * HD);
  TransArgs ta = {Wqa, Wkva, Wqb, Wkvb, Wo, Wqa_t, Wkva_t, Wqb_t, Wkvb_t, Wo_t};
  transpose_all<<<15104, 256, 0, stream>>>(ta);
  // ---- combined first-stage GEMM: xa = x_bf @ [Wqa | Wkva] ----
  gemm_bf16<bf16><<<dim3(NQKVA / 128, NTOK / 128), 256, 0, stream>>>(x_bf, Wqa_t, xa, NTOK, NQKVA, HD);
  // ---- merged norms + rope prep ----
  norm_prep<<<NTOK, 256, 0, stream>>>(xa, g_qa, g_kva, pos, cosT, sinT, q_n, kv_l, k_bhsd);
  // ---- Q path (256^2 counted-vmcnt core) ----
  gemm8p_qf<<<dim3(NQB / 256, NTOK / 256), 512, 0, stream>>>(q_n, Wqb_t, pos, cosT, sinT, q_bhsd);
  // ---- KV path (256^2 counted-vmcnt core; v written transposed directly) ----
  gemm8p_kvb<<<dim3(NKVB / 256, NTOK / 256), 512, 0, stream>>>(kv_l, Wkvb_t, k_bhsd, v_t);
  // ---- attention + output projection ----
  flash6<<<512, 256, 0, stream>>>(q_bhsd, k_bhsd, v_t, att);
  gemm_bf16<float><<<dim3(HD / 128, NTOK / 128), 256, 0, stream>>>(att, Wo_t, out, NTOK, HD, HD);
}

// Round 15
// 298.865 us; speedup vs baseline: 1.0737x; 1.0737x over previous
//
#include <hip/hip_runtime.h>
#include <hip/hip_bf16.h>

typedef __bf16 bf16;
typedef __bf16 bf16x8 __attribute__((ext_vector_type(8)));
typedef __bf16 bf16x4 __attribute__((ext_vector_type(4)));
typedef float f32x4 __attribute__((ext_vector_type(4)));

#define B_    2
#define S_    2048
#define HD    2048
#define NH    16
#define DQK   192
#define DV    128
#define QR    1536
#define KVR   512
#define NTOK  4096
#define NKVB  4096   /* N_HEADS*(D_NOPE+D_V) */
#define NQB   3072   /* N_HEADS*D_QK */
#define NQKVAP 2304  /* QR + 768 (padded kv_a, 9*256) */

#define EXP2F(x) __builtin_amdgcn_exp2f(x)

static __device__ __forceinline__ void gload16(const void* g, void* l) {
  __builtin_amdgcn_global_load_lds(
      (const __attribute__((address_space(1))) void*)g,
      (__attribute__((address_space(3))) void*)l, 16, 0, 0);
}

// ---------------- f32 -> bf16 convert ----------------
__global__ __launch_bounds__(256) void cvt_bf16(const float* __restrict__ in,
                                                bf16* __restrict__ out, long n) {
  long i = ((long)blockIdx.x * 256 + threadIdx.x) * 4;
  if (i + 3 < n) {
    float4 v = *(const float4*)(in + i);
    bf16x4 o = {(bf16)v.x, (bf16)v.y, (bf16)v.z, (bf16)v.w};
    *(bf16x4*)(out + i) = o;
  }
}

// ---------------- merged weight transposes: 5 segments, one launch ------------
// seg1 (Wkva) now pads to 768 rows (zeros beyond col 576) for the 2304-wide
// combined B^T used by the gemm8p xa GEMM.
struct TransArgs {
  const float *s0, *s1, *s2, *s3, *s4;
  bf16 *d0, *d1, *d2, *d3, *d4;
};
__global__ __launch_bounds__(256) void transpose_all(TransArgs a) {
  __shared__ float tile[32][33];
  int bid = blockIdx.x;
  int seg, rel;
  if      (bid < 3072)  { seg = 0; rel = bid; }
  else if (bid < 4608)  { seg = 1; rel = bid - 3072; }
  else if (bid < 9216)  { seg = 2; rel = bid - 4608; }
  else if (bid < 11264) { seg = 3; rel = bid - 9216; }
  else                  { seg = 4; rel = bid - 11264; }
  const float* in = seg == 0 ? a.s0 : seg == 1 ? a.s1 : seg == 2 ? a.s2 : seg == 3 ? a.s3 : a.s4;
  bf16* out       = seg == 0 ? a.d0 : seg == 1 ? a.d1 : seg == 2 ? a.d2 : seg == 3 ? a.d3 : a.d4;
  int R   = seg == 0 ? 2048 : seg == 1 ? 2048 : seg == 2 ? 1536 : seg == 3 ? 512 : 2048;
  int C   = seg == 0 ? 1536 : seg == 1 ? 576  : seg == 2 ? 3072 : seg == 3 ? 4096 : 2048;
  int Np  = seg == 0 ? 1536 : seg == 1 ? 768  : seg == 2 ? 3072 : seg == 3 ? 4096 : 2048;
  int nbx = seg == 0 ? 48   : seg == 1 ? 24   : seg == 2 ? 96   : seg == 3 ? 128 : 64;
  int c0 = (rel % nbx) * 32;
  int r0 = (rel / nbx) * 32;
  int tx = threadIdx.x & 31, ty = threadIdx.x >> 5;
#pragma unroll
  for (int i = 0; i < 4; ++i) {
    int r = r0 + ty + i * 8, c = c0 + tx;
    tile[ty + i * 8][tx] = (c < C) ? in[(long)r * C + c] : 0.f;
  }
  __syncthreads();
#pragma unroll
  for (int i = 0; i < 4; ++i) {
    int oc = c0 + ty + i * 8;
    if (oc < Np) out[(long)oc * R + r0 + tx] = (bf16)tile[tx][ty + i * 8];
  }
}

// ============ shared GEMM core: 128x128 tile, BK=64, XOR chunk swizzle ========
#define GEMM_CORE(A, Bt, K)                                                    \
  __shared__ bf16 As[128 * 64];                                                \
  __shared__ bf16 Bs[128 * 64];                                                \
  const int t = threadIdx.x;                                                   \
  const int l = t & 63;                                                        \
  const int w = t >> 6;                                                        \
  const int m0 = blockIdx.y * 128;                                             \
  const int n0 = blockIdx.x * 128;                                             \
  const int wr = (w >> 1) * 64;                                                \
  const int wc = (w & 1) * 64;                                                 \
  const int lr = l & 15;                                                       \
  const int lg = l >> 4;                                                       \
  f32x4 acc[4][4] = {};                                                        \
  for (int k0 = 0; k0 < (K); k0 += 64) {                                       \
    __syncthreads();                                                           \
    _Pragma("unroll")                                                          \
    for (int j = 0; j < 4; ++j) {                                              \
      int s = j * 256 + t;                                                     \
      int row = s >> 3, sc = s & 7;                                            \
      int c = sc ^ (row & 7);                                                  \
      gload16((A) + (long)(m0 + row) * (K) + k0 + c * 8,                       \
              As + (j * 256 + w * 64) * 8);                                    \
      gload16((Bt) + (long)(n0 + row) * (K) + k0 + c * 8,                      \
              Bs + (j * 256 + w * 64) * 8);                                    \
    }                                                                          \
    __syncthreads();                                                           \
    _Pragma("unroll")                                                          \
    for (int kh = 0; kh < 2; ++kh) {                                           \
      bf16x8 af[4], bfr[4];                                                    \
      _Pragma("unroll")                                                        \
      for (int m = 0; m < 4; ++m) {                                            \
        int row = wr + m * 16 + lr;                                            \
        af[m] = *(const bf16x8*)(As + row * 64 + (((kh * 4 + lg) ^ (row & 7)) << 3)); \
      }                                                                        \
      _Pragma("unroll")                                                        \
      for (int n = 0; n < 4; ++n) {                                            \
        int row = wc + n * 16 + lr;                                            \
        bfr[n] = *(const bf16x8*)(Bs + row * 64 + (((kh * 4 + lg) ^ (row & 7)) << 3)); \
      }                                                                        \
      _Pragma("unroll")                                                        \
      for (int m = 0; m < 4; ++m)                                              \
        _Pragma("unroll")                                                      \
        for (int n = 0; n < 4; ++n)                                            \
          acc[m][n] = __builtin_amdgcn_mfma_f32_16x16x32_bf16(af[m], bfr[n], acc[m][n], 0, 0, 0); \
    }                                                                          \
  }

// ---------------- generic GEMM: C[M][N] = A @ Bt^T ----------------------------
template <typename CT>
__global__ __launch_bounds__(256) void gemm_bf16(const bf16* __restrict__ A,
                                                 const bf16* __restrict__ Bt,
                                                 CT* __restrict__ C,
                                                 int M, int N, int K) {
  GEMM_CORE(A, Bt, K)
#pragma unroll
  for (int m = 0; m < 4; ++m)
#pragma unroll
    for (int n = 0; n < 4; ++n)
#pragma unroll
      for (int v = 0; v < 4; ++v) {
        int row = m0 + wr + m * 16 + lg * 4 + v;
        int col = n0 + wc + n * 16 + lr;
        C[(long)row * N + col] = (CT)acc[m][n][v];
      }
}

// ============ gemm8p core: 256x256 tile, BK=64, 8 waves, 2-dbuf, counted vmcnt
#define G8P_CORE(A, Bt, K)                                                     \
  __shared__ bf16 As_[2][256 * 64];                                            \
  __shared__ bf16 Bs_[2][256 * 64];                                            \
  const int t = threadIdx.x;                                                   \
  const int w = t >> 6, l = t & 63;                                            \
  const int lr = l & 15, lg = l >> 4;                                          \
  const int wm = w >> 2, wn = w & 3;                                           \
  const int m0 = blockIdx.y * 256, n0 = blockIdx.x * 256;                      \
  const int NT = (K) >> 6;                                                     \
  const int tr = t >> 3, sc = t & 7;                                           \
  f32x4 acc[8][4] = {};                                                        \
  auto stg = [&](int kt, int j) {                                              \
    int jj = j & 3;                                                            \
    int row = jj * 64 + tr;                                                    \
    int c = sc ^ (row & 7);                                                    \
    const bf16* src = (j < 4)                                                  \
        ? (A)  + (long)(m0 + row) * (K) + kt * 64 + c * 8                      \
        : (Bt) + (long)(n0 + row) * (K) + kt * 64 + c * 8;                     \
    bf16* dst = ((j < 4) ? As_[kt & 1] : Bs_[kt & 1]) + (jj * 512 + w * 64) * 8; \
    gload16(src, dst);                                                         \
  };                                                                           \
  _Pragma("unroll") for (int j = 0; j < 8; ++j) stg(0, j);                     \
  _Pragma("unroll") for (int j = 0; j < 8; ++j) stg(1, j);                     \
  for (int kt = 0; kt < NT; ++kt) {                                            \
    const bf16* Ab = As_[kt & 1];                                              \
    const bf16* Bb = Bs_[kt & 1];                                              \
    if (kt == NT - 1) { asm volatile("s_waitcnt vmcnt(0)" ::: "memory"); }     \
    else              { asm volatile("s_waitcnt vmcnt(8)" ::: "memory"); }     \
    __builtin_amdgcn_s_barrier();                                              \
    asm volatile("" ::: "memory");                                             \
    bf16x8 af[8][2], bfr[4][2];                                                \
    _Pragma("unroll")                                                          \
    for (int mi = 0; mi < 8; ++mi) {                                           \
      int row = wm * 128 + mi * 16 + lr;                                       \
      _Pragma("unroll")                                                        \
      for (int kh = 0; kh < 2; ++kh)                                           \
        af[mi][kh] = *(const bf16x8*)(Ab + row * 64 + (((kh * 4 + lg) ^ (row & 7)) << 3)); \
    }                                                                          \
    _Pragma("unroll")                                                          \
    for (int ni = 0; ni < 4; ++ni) {                                           \
      int row = wn * 64 + ni * 16 + lr;                                        \
      _Pragma("unroll")                                                        \
      for (int kh = 0; kh < 2; ++kh)                                           \
        bfr[ni][kh] = *(const bf16x8*)(Bb + row * 64 + (((kh * 4 + lg) ^ (row & 7)) << 3)); \
    }                                                                          \
    asm volatile("s_waitcnt lgkmcnt(0)" ::: "memory");                         \
    __builtin_amdgcn_sched_barrier(0);                                         \
    __builtin_amdgcn_s_setprio(1);                                             \
    _Pragma("unroll")                                                          \
    for (int mi = 0; mi < 8; ++mi)                                             \
      _Pragma("unroll")                                                        \
      for (int kh = 0; kh < 2; ++kh)                                           \
        acc[mi][0] = __builtin_amdgcn_mfma_f32_16x16x32_bf16(af[mi][kh], bfr[0][kh], acc[mi][0], 0, 0, 0); \
    __builtin_amdgcn_s_setprio(0);                                             \
    __builtin_amdgcn_s_barrier();  /* all waves' ds_reads done: dbufs free */  \
    asm volatile("" ::: "memory");                                             \
    bool more = (kt + 2) < NT;                                                 \
    if (more) { stg(kt + 2, 0); stg(kt + 2, 1); stg(kt + 2, 2); }              \
    __builtin_amdgcn_s_setprio(1);                                             \
    _Pragma("unroll")                                                          \
    for (int mi = 0; mi < 8; ++mi)                                             \
      _Pragma("unroll")                                                        \
      for (int kh = 0; kh < 2; ++kh)                                           \
        acc[mi][1] = __builtin_amdgcn_mfma_f32_16x16x32_bf16(af[mi][kh], bfr[1][kh], acc[mi][1], 0, 0, 0); \
    __builtin_amdgcn_s_setprio(0);                                             \
    if (more) { stg(kt + 2, 3); stg(kt + 2, 4); stg(kt + 2, 5); }              \
    __builtin_amdgcn_s_setprio(1);                                             \
    _Pragma("unroll")                                                          \
    for (int mi = 0; mi < 8; ++mi)                                             \
      _Pragma("unroll")                                                        \
      for (int kh = 0; kh < 2; ++kh)                                           \
        acc[mi][2] = __builtin_amdgcn_mfma_f32_16x16x32_bf16(af[mi][kh], bfr[2][kh], acc[mi][2], 0, 0, 0); \
    __builtin_amdgcn_s_setprio(0);                                             \
    if (more) { stg(kt + 2, 6); stg(kt + 2, 7); }                              \
    __builtin_amdgcn_s_setprio(1);                                             \
    _Pragma("unroll")                                                          \
    for (int mi = 0; mi < 8; ++mi)                                             \
      _Pragma("unroll")                                                        \
      for (int kh = 0; kh < 2; ++kh)                                           \
        acc[mi][3] = __builtin_amdgcn_mfma_f32_16x16x32_bf16(af[mi][kh], bfr[3][kh], acc[mi][3], 0, 0, 0); \
    __builtin_amdgcn_s_setprio(0);                                             \
  }

// ---------------- gemm8p generic: C[M][N] = A @ Bt^T --------------------------
template <typename CT>
__global__ __launch_bounds__(512) void gemm8p_c(const bf16* __restrict__ A,
                                                const bf16* __restrict__ Bt,
                                                CT* __restrict__ C,
                                                int N, int K) {
  G8P_CORE(A, Bt, K)
#pragma unroll
  for (int mi = 0; mi < 8; ++mi)
#pragma unroll
    for (int ni = 0; ni < 4; ++ni)
#pragma unroll
      for (int v = 0; v < 4; ++v) {
        int row = m0 + wm * 128 + mi * 16 + lg * 4 + v;
        int col = n0 + wn * 64 + ni * 16 + lr;
        C[(long)row * N + col] = (CT)acc[mi][ni][v];
      }
}

// ---------------- gemm8p fused q_f: RoPE + SCALE*LOG2E -> q_bhsd --------------
__global__ __launch_bounds__(512) void gemm8p_qf(const bf16* __restrict__ A,
                                                 const bf16* __restrict__ Bt,
                                                 const int* __restrict__ pos,
                                                 const float* __restrict__ cosT,
                                                 const float* __restrict__ sinT,
                                                 bf16* __restrict__ q_bhsd) {
  const float SCALE = 0.07216878364870323f * 1.4426950408889634f;
  G8P_CORE(A, Bt, QR)
  int c0 = n0 + wn * 64;
  int h = c0 / 192;
  int part = c0 - h * 192;            // 0, 64, or 128 (wave-uniform)
#pragma unroll
  for (int mi = 0; mi < 8; ++mi)
#pragma unroll
    for (int v = 0; v < 4; ++v) {
      int row = m0 + wm * 128 + mi * 16 + lg * 4 + v;
      int b = row >> 11, s = row & (S_ - 1);
      long base = ((long)(b * NH + h) * S_ + s) * DQK;
      if (part < 128) {
#pragma unroll
        for (int ni = 0; ni < 4; ++ni)
          q_bhsd[base + part + ni * 16 + lr] = (bf16)(acc[mi][ni][v] * SCALE);
      } else {
        int p = pos[s] & (S_ - 1);
        float c_lo = cosT[p * 32 + lr],      s_lo = sinT[p * 32 + lr];
        float c_hi = cosT[p * 32 + 16 + lr], s_hi = sinT[p * 32 + 16 + lr];
        float o0 = acc[mi][0][v] * c_lo - acc[mi][2][v] * s_lo;
        float o1 = acc[mi][1][v] * c_hi - acc[mi][3][v] * s_hi;
        float o2 = acc[mi][0][v] * s_lo + acc[mi][2][v] * c_lo;
        float o3 = acc[mi][1][v] * s_hi + acc[mi][3][v] * c_hi;
        q_bhsd[base + 128 + lr] = (bf16)(o0 * SCALE);
        q_bhsd[base + 144 + lr] = (bf16)(o1 * SCALE);
        q_bhsd[base + 160 + lr] = (bf16)(o2 * SCALE);
        q_bhsd[base + 176 + lr] = (bf16)(o3 * SCALE);
      }
    }
}

// ---------------- gemm8p fused kv_b: k -> k_bhsd, v -> v_t (direct transpose) -
__global__ __launch_bounds__(512) void gemm8p_kvb(const bf16* __restrict__ A,
                                                  const bf16* __restrict__ Bt,
                                                  bf16* __restrict__ k_bhsd,
                                                  bf16* __restrict__ v_t) {
  G8P_CORE(A, Bt, KVR)
  int c0 = n0 + wn * 64;
  int h = c0 >> 8;
  int dbase = c0 & 64;
  bool vpart = (c0 >> 7) & 1;
  if (!vpart) {
#pragma unroll
    for (int mi = 0; mi < 8; ++mi)
#pragma unroll
      for (int v = 0; v < 4; ++v) {
        int row = m0 + wm * 128 + mi * 16 + lg * 4 + v;
        int b = row >> 11, s = row & (S_ - 1);
        long base = ((long)(b * NH + h) * S_ + s) * DQK + dbase;
#pragma unroll
        for (int ni = 0; ni < 4; ++ni)
          k_bhsd[base + ni * 16 + lr] = (bf16)acc[mi][ni][v];
      }
  } else {
#pragma unroll
    for (int mi = 0; mi < 8; ++mi) {
      int row0 = m0 + wm * 128 + mi * 16 + lg * 4;
      int b = row0 >> 11, s = row0 & (S_ - 1);
#pragma unroll
      for (int ni = 0; ni < 4; ++ni) {
        int d = dbase + ni * 16 + lr;
        bf16x4 o = {(bf16)acc[mi][ni][0], (bf16)acc[mi][ni][1],
                    (bf16)acc[mi][ni][2], (bf16)acc[mi][ni][3]};
        *(bf16x4*)(v_t + ((long)(b * NH + h) * DV + d) * S_ + s) = o;
      }
    }
  }
}

// ---------------- merged norm+prep: waves 0-2 q-RMSNorm, wave 3 kv+rope -------
__global__ __launch_bounds__(256) void norm_prep(const bf16* __restrict__ xa,   // [NTOK][2304]
                                                 const float* __restrict__ g_qa,
                                                 const float* __restrict__ g_kva,
                                                 const int* __restrict__ pos,
                                                 const float* __restrict__ cosT,
                                                 const float* __restrict__ sinT,
                                                 bf16* __restrict__ q_n,       // [NTOK][1536]
                                                 bf16* __restrict__ kv_l,      // [NTOK][512]
                                                 bf16* __restrict__ k_bhsd) {  // [B][H][S][192]
  int row = blockIdx.x;
  int t = threadIdx.x;
  int b = row >> 11, s = row & (S_ - 1);
  const bf16* xr = xa + (long)row * NQKVAP;
  __shared__ float red[3];
  __shared__ bf16 rope_s[64];
  float vf[8];
  if (t < 192) {
    bf16x8 vv = *(const bf16x8*)(xr + t * 8);
    float ss = 0.f;
#pragma unroll
    for (int e = 0; e < 8; ++e) { vf[e] = (float)vv[e]; ss += vf[e] * vf[e]; }
#pragma unroll
    for (int m = 1; m < 64; m <<= 1) ss += __shfl_xor(ss, m);
    if ((t & 63) == 0) red[t >> 6] = ss;
  } else {
    int tt = t - 192;
    const bf16* xl = xr + QR;
    bf16x8 vv = *(const bf16x8*)(xl + tt * 8);
    float ss = 0.f;
#pragma unroll
    for (int e = 0; e < 8; ++e) { vf[e] = (float)vv[e]; ss += vf[e] * vf[e]; }
#pragma unroll
    for (int m = 1; m < 64; m <<= 1) ss += __shfl_xor(ss, m);
    float rs = rsqrtf(ss / KVR + 1e-5f);
    bf16x8 o;
#pragma unroll
    for (int e = 0; e < 8; ++e) o[e] = (bf16)(vf[e] * rs * g_kva[tt * 8 + e]);
    *(bf16x8*)(kv_l + (long)row * KVR + tt * 8) = o;
    if (tt < 32) {
      int p = pos[s] & (S_ - 1);
      float c = cosT[p * 32 + tt], sn = sinT[p * 32 + tt];
      float x0 = (float)xl[512 + tt], x1 = (float)xl[544 + tt];
      rope_s[tt] = (bf16)(x0 * c - x1 * sn);
      rope_s[32 + tt] = (bf16)(x0 * sn + x1 * c);
    }
  }
  __syncthreads();
  if (t < 192) {
    float ss = red[0] + red[1] + red[2];
    float rs = rsqrtf(ss / QR + 1e-5f);
    bf16x8 o;
#pragma unroll
    for (int e = 0; e < 8; ++e) o[e] = (bf16)(vf[e] * rs * g_qa[t * 8 + e]);
    *(bf16x8*)(q_n + (long)row * QR + t * 8) = o;
  } else {
    int tt = t - 192;
    bf16x8 rv = *(const bf16x8*)&rope_s[(tt & 7) * 8];
    long base0 = ((long)(b * NH + (tt >> 3)) * S_ + s) * DQK + 128 + (tt & 7) * 8;
    long base1 = ((long)(b * NH + 8 + (tt >> 3)) * S_ + s) * DQK + 128 + (tt & 7) * 8;
    *(bf16x8*)(k_bhsd + base0) = rv;
    *(bf16x8*)(k_bhsd + base1) = rv;
  }
}

// ---------------- flash v4 (proven 91us): 8 waves x 16 q-rows, QBLK=128 -------
#define KVB  64
#define DVP  144
__global__ __launch_bounds__(512) void flash4(const bf16* __restrict__ q_bhsd,
                                              const bf16* __restrict__ k_bhsd,
                                              const bf16* __restrict__ v_t,
                                              bf16* __restrict__ att) {  // [NTOK][2048]
  __shared__ bf16 Ks[KVB * DQK];      // 24 KB, swizzled 16B chunks
  __shared__ bf16 Vs[DVP * KVB];      // 18 KB, rows 0-127 staged, 128-143 const
  __shared__ bf16 Ps[8][16 * 72];     // 18 KB, per-wave P, padded to 72
  int bid = blockIdx.x;
  int bh = bid & 31;                  // head-of-batch: fixes XCD = bh%8
  int qt = 15 - (bid >> 5);           // heaviest (most k-tiles) first
  int b = bh >> 4, h = bh & 15;
  int q0 = qt * 128;
  int t = threadIdx.x;
  int w = t >> 6, l = t & 63;
  int lr = l & 15, lg = l >> 4;
  int qw = q0 + w * 16;               // this wave's first q row

  const bf16* Qb = q_bhsd + (long)bh * S_ * DQK;
  const bf16* Kb = k_bhsd + (long)bh * S_ * DQK;
  const bf16* Vb = v_t + (long)bh * DV * S_;

  // init ones/zero rows of Vs (persist across tiles; staging never touches them)
  if (t < 128) {
    int rr = 128 + (t >> 3), cc = (t & 7) * 8;
    bf16 val = (bf16)((rr == 128) ? 1.0f : 0.0f);
    bf16x8 vvv = {val, val, val, val, val, val, val, val};
    *(bf16x8*)(Vs + rr * KVB + cc) = vvv;
  }

  bf16x8 qf[6];
#pragma unroll
  for (int t6 = 0; t6 < 6; ++t6)
    qf[t6] = *(const bf16x8*)(Qb + (long)(qw + lr) * DQK + t6 * 32 + lg * 8);

  f32x4 oacc[9] = {};                 // [0..7] output, [8] = l (ones-row)
  float mrow[4] = {-1e30f, -1e30f, -1e30f, -1e30f};
  const int lr7 = lr & 7;

  int nkt = 2 * qt + 2;
  for (int kt = 0; kt < nkt; ++kt) {
    int k0 = kt * KVB;
    __syncthreads();
    // stage K: 1536 chunks (3 x 512); slot s holds global chunk (r, c^(r&7))
#pragma unroll
    for (int j = 0; j < 3; ++j) {
      int s = j * 512 + t;
      int r = s / 24, c1 = s - r * 24;
      int c = c1 ^ (r & 7);
      gload16(Kb + (long)(k0 + r) * DQK + c * 8, Ks + (j * 512 + w * 64) * 8);
    }
    // stage V: 1024 chunks (2 x 512), rows 0..127 only
#pragma unroll
    for (int j = 0; j < 2; ++j) {
      int s = j * 512 + t;
      int d = s >> 3, c1 = s & 7;
      int c = c1 ^ (d & 7);
      gload16(Vb + (long)d * S_ + k0 + c * 8, Vs + (j * 512 + w * 64) * 8);
    }
    __syncthreads();
    if (k0 > qw + 15) continue;       // fully masked for this wave

    // ---- QK^T: sacc[n] = scores[q=lg*4+v][k=n*16+lr] (log2-domain) ----
    f32x4 sacc[4] = {};
#pragma unroll
    for (int n = 0; n < 4; ++n) {
      int rk = n * 16 + lr;
#pragma unroll
      for (int t6 = 0; t6 < 6; ++t6) {
        bf16x8 kf = *(const bf16x8*)(Ks + rk * DQK + (((t6 * 4 + lg) ^ lr7) << 3));
        sacc[n] = __builtin_amdgcn_mfma_f32_16x16x32_bf16(qf[t6], kf, sacc[n], 0, 0, 0);
      }
    }
    // ---- causal mask (diagonal tiles only) ----
    if (k0 + KVB - 1 > qw) {
#pragma unroll
      for (int n = 0; n < 4; ++n)
#pragma unroll
        for (int v = 0; v < 4; ++v) {
          int r = lg * 4 + v, c = n * 16 + lr;
          if (k0 + c > qw + r) sacc[n][v] = -1e30f;
        }
    }
    // ---- tile row-max ----
    float mv[4];
#pragma unroll
    for (int v = 0; v < 4; ++v) {
      mv[v] = fmaxf(fmaxf(sacc[0][v], sacc[1][v]), fmaxf(sacc[2][v], sacc[3][v]));
#pragma unroll
      for (int msk = 1; msk < 16; msk <<= 1) mv[v] = fmaxf(mv[v], __shfl_xor(mv[v], msk));
    }
    // ---- defer-max: rescale only if some row max grew by > 8 (log2) ----
    bool grow = (mv[0] > mrow[0] + 8.f) | (mv[1] > mrow[1] + 8.f) |
                (mv[2] > mrow[2] + 8.f) | (mv[3] > mrow[3] + 8.f);
    if (__any(grow)) {
      float corr[4];
#pragma unroll
      for (int v = 0; v < 4; ++v) {
        float mt = fmaxf(mrow[v], mv[v]);
        corr[v] = EXP2F(mrow[v] - mt);
        mrow[v] = mt;
      }
#pragma unroll
      for (int dn = 0; dn < 9; ++dn)
#pragma unroll
        for (int v = 0; v < 4; ++v) oacc[dn][v] *= corr[v];
    }
    // ---- P = exp2(s - mrow); P -> LDS (per-wave, padded) ----
#pragma unroll
    for (int v = 0; v < 4; ++v)
#pragma unroll
      for (int n = 0; n < 4; ++n)
        Ps[w][(lg * 4 + v) * 72 + n * 16 + lr] = (bf16)EXP2F(sacc[n][v] - mrow[v]);
    // ---- PV: oacc[dn] += P[16x64] @ V^T; dn=8 hits the ones-row => l ----
#pragma unroll
    for (int kc = 0; kc < 2; ++kc) {
      bf16x8 pf = *(const bf16x8*)(Ps[w] + lr * 72 + kc * 32 + lg * 8);
#pragma unroll
      for (int dn = 0; dn < 9; ++dn) {
        int d = dn * 16 + lr;
        bf16x8 vf = *(const bf16x8*)(Vs + d * KVB + (((kc * 4 + lg) ^ lr7) << 3));
        oacc[dn] = __builtin_amdgcn_mfma_f32_16x16x32_bf16(pf, vf, oacc[dn], 0, 0, 0);
      }
    }
  }
  // ---- epilogue: l lives in column d=128 (lanes lr==0); broadcast + divide ----
  float rl[4];
#pragma unroll
  for (int v = 0; v < 4; ++v) {
    float lv = __shfl(oacc[8][v], lg * 16);
    rl[v] = 1.0f / lv;
  }
#pragma unroll
  for (int dn = 0; dn < 8; ++dn)
#pragma unroll
    for (int v = 0; v < 4; ++v) {
      int r = lg * 4 + v;
      float o = oacc[dn][v] * rl[v];
      att[((long)(b * S_ + qw + r)) * 2048 + h * 128 + dn * 16 + lr] = (bf16)o;
    }
}

extern "C" void kernel_launch(void* const* d_in, const int* in_sizes, int n_in,
                              void* d_out, int out_size, void* d_ws, size_t ws_size,
                              hipStream_t stream) {
  const float* x        = (const float*)d_in[0];
  const int* pos        = (const int*)d_in[1];   // harness passes integers as int32
  const float* Wqa      = (const float*)d_in[2];
  const float* g_qa     = (const float*)d_in[3];
  const float* Wqb      = (const float*)d_in[4];
  const float* Wkva     = (const float*)d_in[5];
  const float* g_kva    = (const float*)d_in[6];
  const float* Wkvb     = (const float*)d_in[7];
  const float* Wo       = (const float*)d_in[8];
  const float* cosT     = (const float*)d_in[9];
  const float* sinT     = (const float*)d_in[10];
  float* out            = (float*)d_out;

  // ---- workspace layout ----
  size_t off = 0;
  char* wsp = (char*)d_ws;
  auto alloc = [&](size_t n) { void* p = wsp + off; off += (n + 255) & ~(size_t)255; return p; };
  bf16*  Wqa_t  = (bf16*) alloc((size_t)QR * HD * 2);      // contiguous with
  bf16*  Wkva_t = (bf16*) alloc((size_t)768 * HD * 2);     //  ... Wqa_t (2304-row Bt)
  bf16*  Wqb_t  = (bf16*) alloc((size_t)NQB * QR * 2);
  bf16*  Wkvb_t = (bf16*) alloc((size_t)NKVB * KVR * 2);
  bf16*  Wo_t   = (bf16*) alloc((size_t)HD * HD * 2);
  bf16*  x_bf   = (bf16*) alloc((size_t)NTOK * HD * 2);
  bf16*  q_bhsd = (bf16*) alloc((size_t)B_ * NH * S_ * DQK * 2);
  bf16*  k_bhsd = (bf16*) alloc((size_t)B_ * NH * S_ * DQK * 2);
  bf16*  v_t    = (bf16*) alloc((size_t)B_ * NH * DV * S_ * 2);
  bf16*  att    = (bf16*) alloc((size_t)NTOK * 2048 * 2);
  char*  T      = (char*) alloc((size_t)37748736);         // 36 MB transient
  bf16*  xa  = (bf16*)T;                        // [NTOK][2304] = 18.87 MB
  bf16*  q_n = (bf16*)(T + 18874368);           // [NTOK][1536] = 12.6 MB
  bf16*  kv_l = (bf16*)(T + 18874368 + 12582912); // [NTOK][512] = 4.2 MB
  if (ws_size < off) return;

  cvt_bf16<<<(NTOK * HD / 4 + 255) / 256, 256, 0, stream>>>(x, x_bf, (long)NTOK * HD);
  TransArgs ta = {Wqa, Wkva, Wqb, Wkvb, Wo, Wqa_t, Wkva_t, Wqb_t, Wkvb_t, Wo_t};
  transpose_all<<<15360, 256, 0, stream>>>(ta);
  // ---- combined first-stage GEMM (gemm8p, N padded to 2304): xa = x_bf @ W ---
  gemm8p_c<bf16><<<dim3(NQKVAP / 256, NTOK / 256), 512, 0, stream>>>(x_bf, Wqa_t, xa, NQKVAP, HD);
  // ---- merged norms + rope prep ----
  norm_prep<<<NTOK, 256, 0, stream>>>(xa, g_qa, g_kva, pos, cosT, sinT, q_n, kv_l, k_bhsd);
  // ---- Q path (256^2 counted-vmcnt core) ----
  gemm8p_qf<<<dim3(NQB / 256, NTOK / 256), 512, 0, stream>>>(q_n, Wqb_t, pos, cosT, sinT, q_bhsd);
  // ---- KV path (256^2 counted-vmcnt core; v written transposed directly) ----
  gemm8p_kvb<<<dim3(NKVB / 256, NTOK / 256), 512, 0, stream>>>(kv_l, Wkvb_t, k_bhsd, v_t);
  // ---- attention + output projection ----
  flash4<<<512, 512, 0, stream>>>(q_bhsd, k_bhsd, v_t, att);
  gemm_bf16<float><<<dim3(HD / 128, NTOK / 128), 256, 0, stream>>>(att, Wo_t, out, NTOK, HD, HD);
}

// Round 16
// 296.773 us; speedup vs baseline: 1.0813x; 1.0070x over previous
//
#include <hip/hip_runtime.h>
#include <hip/hip_bf16.h>

typedef __bf16 bf16;
typedef __bf16 bf16x8 __attribute__((ext_vector_type(8)));
typedef __bf16 bf16x4 __attribute__((ext_vector_type(4)));
typedef float f32x4 __attribute__((ext_vector_type(4)));

#define B_    2
#define S_    2048
#define HD    2048
#define NH    16
#define DQK   192
#define DV    128
#define QR    1536
#define KVR   512
#define NTOK  4096
#define NKVB  4096   /* N_HEADS*(D_NOPE+D_V) */
#define NQB   3072   /* N_HEADS*D_QK */
#define NQKVAP 2304  /* QR + 768 (padded kv_a, 9*256) */

#define EXP2F(x) __builtin_amdgcn_exp2f(x)

static __device__ __forceinline__ void gload16(const void* g, void* l) {
  __builtin_amdgcn_global_load_lds(
      (const __attribute__((address_space(1))) void*)g,
      (__attribute__((address_space(3))) void*)l, 16, 0, 0);
}

// ---------------- merged weight transposes + x f32->bf16 copy (seg5) ----------
struct TransArgs {
  const float *s0, *s1, *s2, *s3, *s4, *x;
  bf16 *d0, *d1, *d2, *d3, *d4, *xb;
};
__global__ __launch_bounds__(256) void transpose_all(TransArgs a) {
  __shared__ float tile[32][33];
  int bid = blockIdx.x;
  if (bid >= 15360) {                 // seg5: x f32 -> bf16 straight copy
    long i = ((long)(bid - 15360) * 256 + threadIdx.x) * 4;
    float4 v = *(const float4*)(a.x + i);
    bf16x4 o = {(bf16)v.x, (bf16)v.y, (bf16)v.z, (bf16)v.w};
    *(bf16x4*)(a.xb + i) = o;
    return;
  }
  int seg, rel;
  if      (bid < 3072)  { seg = 0; rel = bid; }
  else if (bid < 4608)  { seg = 1; rel = bid - 3072; }
  else if (bid < 9216)  { seg = 2; rel = bid - 4608; }
  else if (bid < 11264) { seg = 3; rel = bid - 9216; }
  else                  { seg = 4; rel = bid - 11264; }
  const float* in = seg == 0 ? a.s0 : seg == 1 ? a.s1 : seg == 2 ? a.s2 : seg == 3 ? a.s3 : a.s4;
  bf16* out       = seg == 0 ? a.d0 : seg == 1 ? a.d1 : seg == 2 ? a.d2 : seg == 3 ? a.d3 : a.d4;
  int R   = seg == 0 ? 2048 : seg == 1 ? 2048 : seg == 2 ? 1536 : seg == 3 ? 512 : 2048;
  int C   = seg == 0 ? 1536 : seg == 1 ? 576  : seg == 2 ? 3072 : seg == 3 ? 4096 : 2048;
  int Np  = seg == 0 ? 1536 : seg == 1 ? 768  : seg == 2 ? 3072 : seg == 3 ? 4096 : 2048;
  int nbx = seg == 0 ? 48   : seg == 1 ? 24   : seg == 2 ? 96   : seg == 3 ? 128 : 64;
  int c0 = (rel % nbx) * 32;
  int r0 = (rel / nbx) * 32;
  int tx = threadIdx.x & 31, ty = threadIdx.x >> 5;
#pragma unroll
  for (int i = 0; i < 4; ++i) {
    int r = r0 + ty + i * 8, c = c0 + tx;
    tile[ty + i * 8][tx] = (c < C) ? in[(long)r * C + c] : 0.f;
  }
  __syncthreads();
#pragma unroll
  for (int i = 0; i < 4; ++i) {
    int oc = c0 + ty + i * 8;
    if (oc < Np) out[(long)oc * R + r0 + tx] = (bf16)tile[tx][ty + i * 8];
  }
}

// ============ shared GEMM core: 128x128 tile, BK=64, XOR chunk swizzle ========
#define GEMM_CORE(A, Bt, K)                                                    \
  __shared__ bf16 As[128 * 64];                                                \
  __shared__ bf16 Bs[128 * 64];                                                \
  const int t = threadIdx.x;                                                   \
  const int l = t & 63;                                                        \
  const int w = t >> 6;                                                        \
  const int m0 = blockIdx.y * 128;                                             \
  const int n0 = blockIdx.x * 128;                                             \
  const int wr = (w >> 1) * 64;                                                \
  const int wc = (w & 1) * 64;                                                 \
  const int lr = l & 15;                                                       \
  const int lg = l >> 4;                                                       \
  f32x4 acc[4][4] = {};                                                        \
  for (int k0 = 0; k0 < (K); k0 += 64) {                                       \
    __syncthreads();                                                           \
    _Pragma("unroll")                                                          \
    for (int j = 0; j < 4; ++j) {                                              \
      int s = j * 256 + t;                                                     \
      int row = s >> 3, sc = s & 7;                                            \
      int c = sc ^ (row & 7);                                                  \
      gload16((A) + (long)(m0 + row) * (K) + k0 + c * 8,                       \
              As + (j * 256 + w * 64) * 8);                                    \
      gload16((Bt) + (long)(n0 + row) * (K) + k0 + c * 8,                      \
              Bs + (j * 256 + w * 64) * 8);                                    \
    }                                                                          \
    __syncthreads();                                                           \
    _Pragma("unroll")                                                          \
    for (int kh = 0; kh < 2; ++kh) {                                           \
      bf16x8 af[4], bfr[4];                                                    \
      _Pragma("unroll")                                                        \
      for (int m = 0; m < 4; ++m) {                                            \
        int row = wr + m * 16 + lr;                                            \
        af[m] = *(const bf16x8*)(As + row * 64 + (((kh * 4 + lg) ^ (row & 7)) << 3)); \
      }                                                                        \
      _Pragma("unroll")                                                        \
      for (int n = 0; n < 4; ++n) {                                            \
        int row = wc + n * 16 + lr;                                            \
        bfr[n] = *(const bf16x8*)(Bs + row * 64 + (((kh * 4 + lg) ^ (row & 7)) << 3)); \
      }                                                                        \
      _Pragma("unroll")                                                        \
      for (int m = 0; m < 4; ++m)                                              \
        _Pragma("unroll")                                                      \
        for (int n = 0; n < 4; ++n)                                            \
          acc[m][n] = __builtin_amdgcn_mfma_f32_16x16x32_bf16(af[m], bfr[n], acc[m][n], 0, 0, 0); \
    }                                                                          \
  }

// ---------------- generic GEMM: C[M][N] = A @ Bt^T ----------------------------
template <typename CT>
__global__ __launch_bounds__(256) void gemm_bf16(const bf16* __restrict__ A,
                                                 const bf16* __restrict__ Bt,
                                                 CT* __restrict__ C,
                                                 int M, int N, int K) {
  GEMM_CORE(A, Bt, K)
#pragma unroll
  for (int m = 0; m < 4; ++m)
#pragma unroll
    for (int n = 0; n < 4; ++n)
#pragma unroll
      for (int v = 0; v < 4; ++v) {
        int row = m0 + wr + m * 16 + lg * 4 + v;
        int col = n0 + wc + n * 16 + lr;
        C[(long)row * N + col] = (CT)acc[m][n][v];
      }
}

// ============ gemm8p body: 256x256 tile, BK=64, 8 waves, 2-dbuf, counted vmcnt
// Requires __shared__ bf16 As_[2][256*64], Bs_[2][256*64] in enclosing scope.
#define G8P_BODY(A, Bt, K, M0, N0)                                             \
  const int t = threadIdx.x;                                                   \
  const int w = t >> 6, l = t & 63;                                            \
  const int lr = l & 15, lg = l >> 4;                                          \
  const int wm = w >> 2, wn = w & 3;                                           \
  const int m0 = (M0), n0 = (N0);                                              \
  const int NT = (K) >> 6;                                                     \
  const int tr = t >> 3, sc = t & 7;                                           \
  f32x4 acc[8][4] = {};                                                        \
  auto stg = [&](int kt, int j) {                                              \
    int jj = j & 3;                                                            \
    int row = jj * 64 + tr;                                                    \
    int c = sc ^ (row & 7);                                                    \
    const bf16* src = (j < 4)                                                  \
        ? (A)  + (long)(m0 + row) * (K) + kt * 64 + c * 8                      \
        : (Bt) + (long)(n0 + row) * (K) + kt * 64 + c * 8;                     \
    bf16* dst = ((j < 4) ? As_[kt & 1] : Bs_[kt & 1]) + (jj * 512 + w * 64) * 8; \
    gload16(src, dst);                                                         \
  };                                                                           \
  _Pragma("unroll") for (int j = 0; j < 8; ++j) stg(0, j);                     \
  _Pragma("unroll") for (int j = 0; j < 8; ++j) stg(1, j);                     \
  for (int kt = 0; kt < NT; ++kt) {                                            \
    const bf16* Ab = As_[kt & 1];                                              \
    const bf16* Bb = Bs_[kt & 1];                                              \
    if (kt == NT - 1) { asm volatile("s_waitcnt vmcnt(0)" ::: "memory"); }     \
    else              { asm volatile("s_waitcnt vmcnt(8)" ::: "memory"); }     \
    __builtin_amdgcn_s_barrier();                                              \
    asm volatile("" ::: "memory");                                             \
    bf16x8 af[8][2], bfr[4][2];                                                \
    _Pragma("unroll")                                                          \
    for (int mi = 0; mi < 8; ++mi) {                                           \
      int row = wm * 128 + mi * 16 + lr;                                       \
      _Pragma("unroll")                                                        \
      for (int kh = 0; kh < 2; ++kh)                                           \
        af[mi][kh] = *(const bf16x8*)(Ab + row * 64 + (((kh * 4 + lg) ^ (row & 7)) << 3)); \
    }                                                                          \
    _Pragma("unroll")                                                          \
    for (int ni = 0; ni < 4; ++ni) {                                           \
      int row = wn * 64 + ni * 16 + lr;                                        \
      _Pragma("unroll")                                                        \
      for (int kh = 0; kh < 2; ++kh)                                           \
        bfr[ni][kh] = *(const bf16x8*)(Bb + row * 64 + (((kh * 4 + lg) ^ (row & 7)) << 3)); \
    }                                                                          \
    asm volatile("s_waitcnt lgkmcnt(0)" ::: "memory");                         \
    __builtin_amdgcn_sched_barrier(0);                                         \
    __builtin_amdgcn_s_setprio(1);                                             \
    _Pragma("unroll")                                                          \
    for (int mi = 0; mi < 8; ++mi)                                             \
      _Pragma("unroll")                                                        \
      for (int kh = 0; kh < 2; ++kh)                                           \
        acc[mi][0] = __builtin_amdgcn_mfma_f32_16x16x32_bf16(af[mi][kh], bfr[0][kh], acc[mi][0], 0, 0, 0); \
    __builtin_amdgcn_s_setprio(0);                                             \
    __builtin_amdgcn_s_barrier();  /* all waves' ds_reads done: dbufs free */  \
    asm volatile("" ::: "memory");                                             \
    bool more = (kt + 2) < NT;                                                 \
    if (more) { stg(kt + 2, 0); stg(kt + 2, 1); stg(kt + 2, 2); }              \
    __builtin_amdgcn_s_setprio(1);                                             \
    _Pragma("unroll")                                                          \
    for (int mi = 0; mi < 8; ++mi)                                             \
      _Pragma("unroll")                                                        \
      for (int kh = 0; kh < 2; ++kh)                                           \
        acc[mi][1] = __builtin_amdgcn_mfma_f32_16x16x32_bf16(af[mi][kh], bfr[1][kh], acc[mi][1], 0, 0, 0); \
    __builtin_amdgcn_s_setprio(0);                                             \
    if (more) { stg(kt + 2, 3); stg(kt + 2, 4); stg(kt + 2, 5); }              \
    __builtin_amdgcn_s_setprio(1);                                             \
    _Pragma("unroll")                                                          \
    for (int mi = 0; mi < 8; ++mi)                                             \
      _Pragma("unroll")                                                        \
      for (int kh = 0; kh < 2; ++kh)                                           \
        acc[mi][2] = __builtin_amdgcn_mfma_f32_16x16x32_bf16(af[mi][kh], bfr[2][kh], acc[mi][2], 0, 0, 0); \
    __builtin_amdgcn_s_setprio(0);                                             \
    if (more) { stg(kt + 2, 6); stg(kt + 2, 7); }                              \
    __builtin_amdgcn_s_setprio(1);                                             \
    _Pragma("unroll")                                                          \
    for (int mi = 0; mi < 8; ++mi)                                             \
      _Pragma("unroll")                                                        \
      for (int kh = 0; kh < 2; ++kh)                                           \
        acc[mi][3] = __builtin_amdgcn_mfma_f32_16x16x32_bf16(af[mi][kh], bfr[3][kh], acc[mi][3], 0, 0, 0); \
    __builtin_amdgcn_s_setprio(0);                                             \
  }

// ---------------- gemm8p generic: C[M][N] = A @ Bt^T (xa GEMM) ----------------
template <typename CT>
__global__ __launch_bounds__(512) void gemm8p_c(const bf16* __restrict__ A,
                                                const bf16* __restrict__ Bt,
                                                CT* __restrict__ C,
                                                int N, int K) {
  __shared__ bf16 As_[2][256 * 64];
  __shared__ bf16 Bs_[2][256 * 64];
  G8P_BODY(A, Bt, K, blockIdx.y * 256, blockIdx.x * 256)
#pragma unroll
  for (int mi = 0; mi < 8; ++mi)
#pragma unroll
    for (int ni = 0; ni < 4; ++ni)
#pragma unroll
      for (int v = 0; v < 4; ++v) {
        int row = m0 + wm * 128 + mi * 16 + lg * 4 + v;
        int col = n0 + wn * 64 + ni * 16 + lr;
        C[(long)row * N + col] = (CT)acc[mi][ni][v];
      }
}

// ---------------- merged qf+kvb gemm8p launch (448 blocks, uniform branch) ----
// blocks [0,192): q_f GEMM with RoPE+SCALE*LOG2E epilogue -> q_bhsd
// blocks [192,448): kv_b GEMM, k-part -> k_bhsd, v-part -> v_t (transposed)
__global__ __launch_bounds__(512) void gemm8p_qkv(
    const bf16* __restrict__ q_n,  const bf16* __restrict__ Wqb_t,
    const bf16* __restrict__ kv_l, const bf16* __restrict__ Wkvb_t,
    const int* __restrict__ pos,
    const float* __restrict__ cosT, const float* __restrict__ sinT,
    bf16* __restrict__ q_bhsd, bf16* __restrict__ k_bhsd,
    bf16* __restrict__ v_t) {
  __shared__ bf16 As_[2][256 * 64];
  __shared__ bf16 Bs_[2][256 * 64];
  int bid = blockIdx.x;
  if (bid < 192) {
    // ---- q_f path: M=4096, N=3072, K=1536; grid 12 x 16 flattened ----
    const float SCALE = 0.07216878364870323f * 1.4426950408889634f;
    int bx = bid % 12, by = bid / 12;
    G8P_BODY(q_n, Wqb_t, QR, by * 256, bx * 256)
    int c0 = n0 + wn * 64;
    int h = c0 / 192;
    int part = c0 - h * 192;          // 0, 64, or 128 (wave-uniform)
#pragma unroll
    for (int mi = 0; mi < 8; ++mi)
#pragma unroll
      for (int v = 0; v < 4; ++v) {
        int row = m0 + wm * 128 + mi * 16 + lg * 4 + v;
        int b = row >> 11, s = row & (S_ - 1);
        long base = ((long)(b * NH + h) * S_ + s) * DQK;
        if (part < 128) {
#pragma unroll
          for (int ni = 0; ni < 4; ++ni)
            q_bhsd[base + part + ni * 16 + lr] = (bf16)(acc[mi][ni][v] * SCALE);
        } else {
          int p = pos[s] & (S_ - 1);
          float c_lo = cosT[p * 32 + lr],      s_lo = sinT[p * 32 + lr];
          float c_hi = cosT[p * 32 + 16 + lr], s_hi = sinT[p * 32 + 16 + lr];
          float o0 = acc[mi][0][v] * c_lo - acc[mi][2][v] * s_lo;
          float o1 = acc[mi][1][v] * c_hi - acc[mi][3][v] * s_hi;
          float o2 = acc[mi][0][v] * s_lo + acc[mi][2][v] * c_lo;
          float o3 = acc[mi][1][v] * s_hi + acc[mi][3][v] * c_hi;
          q_bhsd[base + 128 + lr] = (bf16)(o0 * SCALE);
          q_bhsd[base + 144 + lr] = (bf16)(o1 * SCALE);
          q_bhsd[base + 160 + lr] = (bf16)(o2 * SCALE);
          q_bhsd[base + 176 + lr] = (bf16)(o3 * SCALE);
        }
      }
  } else {
    // ---- kv_b path: M=4096, N=4096, K=512; grid 16 x 16 flattened ----
    int rel = bid - 192;
    int bx = rel & 15, by = rel >> 4;
    G8P_BODY(kv_l, Wkvb_t, KVR, by * 256, bx * 256)
    int c0 = n0 + wn * 64;
    int h = c0 >> 8;
    int dbase = c0 & 64;
    bool vpart = (c0 >> 7) & 1;
    if (!vpart) {
#pragma unroll
      for (int mi = 0; mi < 8; ++mi)
#pragma unroll
        for (int v = 0; v < 4; ++v) {
          int row = m0 + wm * 128 + mi * 16 + lg * 4 + v;
          int b = row >> 11, s = row & (S_ - 1);
          long base = ((long)(b * NH + h) * S_ + s) * DQK + dbase;
#pragma unroll
          for (int ni = 0; ni < 4; ++ni)
            k_bhsd[base + ni * 16 + lr] = (bf16)acc[mi][ni][v];
        }
    } else {
#pragma unroll
      for (int mi = 0; mi < 8; ++mi) {
        int row0 = m0 + wm * 128 + mi * 16 + lg * 4;
        int b = row0 >> 11, s = row0 & (S_ - 1);
#pragma unroll
        for (int ni = 0; ni < 4; ++ni) {
          int d = dbase + ni * 16 + lr;
          bf16x4 o = {(bf16)acc[mi][ni][0], (bf16)acc[mi][ni][1],
                      (bf16)acc[mi][ni][2], (bf16)acc[mi][ni][3]};
          *(bf16x4*)(v_t + ((long)(b * NH + h) * DV + d) * S_ + s) = o;
        }
      }
    }
  }
}

// ---------------- merged norm+prep: waves 0-2 q-RMSNorm, wave 3 kv+rope -------
__global__ __launch_bounds__(256) void norm_prep(const bf16* __restrict__ xa,   // [NTOK][2304]
                                                 const float* __restrict__ g_qa,
                                                 const float* __restrict__ g_kva,
                                                 const int* __restrict__ pos,
                                                 const float* __restrict__ cosT,
                                                 const float* __restrict__ sinT,
                                                 bf16* __restrict__ q_n,       // [NTOK][1536]
                                                 bf16* __restrict__ kv_l,      // [NTOK][512]
                                                 bf16* __restrict__ k_bhsd) {  // [B][H][S][192]
  int row = blockIdx.x;
  int t = threadIdx.x;
  int b = row >> 11, s = row & (S_ - 1);
  const bf16* xr = xa + (long)row * NQKVAP;
  __shared__ float red[3];
  __shared__ bf16 rope_s[64];
  float vf[8];
  if (t < 192) {
    bf16x8 vv = *(const bf16x8*)(xr + t * 8);
    float ss = 0.f;
#pragma unroll
    for (int e = 0; e < 8; ++e) { vf[e] = (float)vv[e]; ss += vf[e] * vf[e]; }
#pragma unroll
    for (int m = 1; m < 64; m <<= 1) ss += __shfl_xor(ss, m);
    if ((t & 63) == 0) red[t >> 6] = ss;
  } else {
    int tt = t - 192;
    const bf16* xl = xr + QR;
    bf16x8 vv = *(const bf16x8*)(xl + tt * 8);
    float ss = 0.f;
#pragma unroll
    for (int e = 0; e < 8; ++e) { vf[e] = (float)vv[e]; ss += vf[e] * vf[e]; }
#pragma unroll
    for (int m = 1; m < 64; m <<= 1) ss += __shfl_xor(ss, m);
    float rs = rsqrtf(ss / KVR + 1e-5f);
    bf16x8 o;
#pragma unroll
    for (int e = 0; e < 8; ++e) o[e] = (bf16)(vf[e] * rs * g_kva[tt * 8 + e]);
    *(bf16x8*)(kv_l + (long)row * KVR + tt * 8) = o;
    if (tt < 32) {
      int p = pos[s] & (S_ - 1);
      float c = cosT[p * 32 + tt], sn = sinT[p * 32 + tt];
      float x0 = (float)xl[512 + tt], x1 = (float)xl[544 + tt];
      rope_s[tt] = (bf16)(x0 * c - x1 * sn);
      rope_s[32 + tt] = (bf16)(x0 * sn + x1 * c);
    }
  }
  __syncthreads();
  if (t < 192) {
    float ss = red[0] + red[1] + red[2];
    float rs = rsqrtf(ss / QR + 1e-5f);
    bf16x8 o;
#pragma unroll
    for (int e = 0; e < 8; ++e) o[e] = (bf16)(vf[e] * rs * g_qa[t * 8 + e]);
    *(bf16x8*)(q_n + (long)row * QR + t * 8) = o;
  } else {
    int tt = t - 192;
    bf16x8 rv = *(const bf16x8*)&rope_s[(tt & 7) * 8];
    long base0 = ((long)(b * NH + (tt >> 3)) * S_ + s) * DQK + 128 + (tt & 7) * 8;
    long base1 = ((long)(b * NH + 8 + (tt >> 3)) * S_ + s) * DQK + 128 + (tt & 7) * 8;
    *(bf16x8*)(k_bhsd + base0) = rv;
    *(bf16x8*)(k_bhsd + base1) = rv;
  }
}

// ---------------- flash v4 (proven 91us): 8 waves x 16 q-rows, QBLK=128 -------
#define KVB  64
#define DVP  144
__global__ __launch_bounds__(512) void flash4(const bf16* __restrict__ q_bhsd,
                                              const bf16* __restrict__ k_bhsd,
                                              const bf16* __restrict__ v_t,
                                              bf16* __restrict__ att) {  // [NTOK][2048]
  __shared__ bf16 Ks[KVB * DQK];      // 24 KB, swizzled 16B chunks
  __shared__ bf16 Vs[DVP * KVB];      // 18 KB, rows 0-127 staged, 128-143 const
  __shared__ bf16 Ps[8][16 * 72];     // 18 KB, per-wave P, padded to 72
  int bid = blockIdx.x;
  int bh = bid & 31;                  // head-of-batch: fixes XCD = bh%8
  int qt = 15 - (bid >> 5);           // heaviest (most k-tiles) first
  int b = bh >> 4, h = bh & 15;
  int q0 = qt * 128;
  int t = threadIdx.x;
  int w = t >> 6, l = t & 63;
  int lr = l & 15, lg = l >> 4;
  int qw = q0 + w * 16;               // this wave's first q row

  const bf16* Qb = q_bhsd + (long)bh * S_ * DQK;
  const bf16* Kb = k_bhsd + (long)bh * S_ * DQK;
  const bf16* Vb = v_t + (long)bh * DV * S_;

  // init ones/zero rows of Vs (persist across tiles; staging never touches them)
  if (t < 128) {
    int rr = 128 + (t >> 3), cc = (t & 7) * 8;
    bf16 val = (bf16)((rr == 128) ? 1.0f : 0.0f);
    bf16x8 vvv = {val, val, val, val, val, val, val, val};
    *(bf16x8*)(Vs + rr * KVB + cc) = vvv;
  }

  bf16x8 qf[6];
#pragma unroll
  for (int t6 = 0; t6 < 6; ++t6)
    qf[t6] = *(const bf16x8*)(Qb + (long)(qw + lr) * DQK + t6 * 32 + lg * 8);

  f32x4 oacc[9] = {};                 // [0..7] output, [8] = l (ones-row)
  float mrow[4] = {-1e30f, -1e30f, -1e30f, -1e30f};
  const int lr7 = lr & 7;

  int nkt = 2 * qt + 2;
  for (int kt = 0; kt < nkt; ++kt) {
    int k0 = kt * KVB;
    __syncthreads();
    // stage K: 1536 chunks (3 x 512); slot s holds global chunk (r, c^(r&7))
#pragma unroll
    for (int j = 0; j < 3; ++j) {
      int s = j * 512 + t;
      int r = s / 24, c1 = s - r * 24;
      int c = c1 ^ (r & 7);
      gload16(Kb + (long)(k0 + r) * DQK + c * 8, Ks + (j * 512 + w * 64) * 8);
    }
    // stage V: 1024 chunks (2 x 512), rows 0..127 only
#pragma unroll
    for (int j = 0; j < 2; ++j) {
      int s = j * 512 + t;
      int d = s >> 3, c1 = s & 7;
      int c = c1 ^ (d & 7);
      gload16(Vb + (long)d * S_ + k0 + c * 8, Vs + (j * 512 + w * 64) * 8);
    }
    __syncthreads();
    if (k0 > qw + 15) continue;       // fully masked for this wave

    // ---- QK^T: sacc[n] = scores[q=lg*4+v][k=n*16+lr] (log2-domain) ----
    f32x4 sacc[4] = {};
#pragma unroll
    for (int n = 0; n < 4; ++n) {
      int rk = n * 16 + lr;
#pragma unroll
      for (int t6 = 0; t6 < 6; ++t6) {
        bf16x8 kf = *(const bf16x8*)(Ks + rk * DQK + (((t6 * 4 + lg) ^ lr7) << 3));
        sacc[n] = __builtin_amdgcn_mfma_f32_16x16x32_bf16(qf[t6], kf, sacc[n], 0, 0, 0);
      }
    }
    // ---- causal mask (diagonal tiles only) ----
    if (k0 + KVB - 1 > qw) {
#pragma unroll
      for (int n = 0; n < 4; ++n)
#pragma unroll
        for (int v = 0; v < 4; ++v) {
          int r = lg * 4 + v, c = n * 16 + lr;
          if (k0 + c > qw + r) sacc[n][v] = -1e30f;
        }
    }
    // ---- tile row-max ----
    float mv[4];
#pragma unroll
    for (int v = 0; v < 4; ++v) {
      mv[v] = fmaxf(fmaxf(sacc[0][v], sacc[1][v]), fmaxf(sacc[2][v], sacc[3][v]));
#pragma unroll
      for (int msk = 1; msk < 16; msk <<= 1) mv[v] = fmaxf(mv[v], __shfl_xor(mv[v], msk));
    }
    // ---- defer-max: rescale only if some row max grew by > 8 (log2) ----
    bool grow = (mv[0] > mrow[0] + 8.f) | (mv[1] > mrow[1] + 8.f) |
                (mv[2] > mrow[2] + 8.f) | (mv[3] > mrow[3] + 8.f);
    if (__any(grow)) {
      float corr[4];
#pragma unroll
      for (int v = 0; v < 4; ++v) {
        float mt = fmaxf(mrow[v], mv[v]);
        corr[v] = EXP2F(mrow[v] - mt);
        mrow[v] = mt;
      }
#pragma unroll
      for (int dn = 0; dn < 9; ++dn)
#pragma unroll
        for (int v = 0; v < 4; ++v) oacc[dn][v] *= corr[v];
    }
    // ---- P = exp2(s - mrow); P -> LDS (per-wave, padded) ----
#pragma unroll
    for (int v = 0; v < 4; ++v)
#pragma unroll
      for (int n = 0; n < 4; ++n)
        Ps[w][(lg * 4 + v) * 72 + n * 16 + lr] = (bf16)EXP2F(sacc[n][v] - mrow[v]);
    // ---- PV: oacc[dn] += P[16x64] @ V^T; dn=8 hits the ones-row => l ----
#pragma unroll
    for (int kc = 0; kc < 2; ++kc) {
      bf16x8 pf = *(const bf16x8*)(Ps[w] + lr * 72 + kc * 32 + lg * 8);
#pragma unroll
      for (int dn = 0; dn < 9; ++dn) {
        int d = dn * 16 + lr;
        bf16x8 vf = *(const bf16x8*)(Vs + d * KVB + (((kc * 4 + lg) ^ lr7) << 3));
        oacc[dn] = __builtin_amdgcn_mfma_f32_16x16x32_bf16(pf, vf, oacc[dn], 0, 0, 0);
      }
    }
  }
  // ---- epilogue: l lives in column d=128 (lanes lr==0); broadcast + divide ----
  float rl[4];
#pragma unroll
  for (int v = 0; v < 4; ++v) {
    float lv = __shfl(oacc[8][v], lg * 16);
    rl[v] = 1.0f / lv;
  }
#pragma unroll
  for (int dn = 0; dn < 8; ++dn)
#pragma unroll
    for (int v = 0; v < 4; ++v) {
      int r = lg * 4 + v;
      float o = oacc[dn][v] * rl[v];
      att[((long)(b * S_ + qw + r)) * 2048 + h * 128 + dn * 16 + lr] = (bf16)o;
    }
}

extern "C" void kernel_launch(void* const* d_in, const int* in_sizes, int n_in,
                              void* d_out, int out_size, void* d_ws, size_t ws_size,
                              hipStream_t stream) {
  const float* x        = (const float*)d_in[0];
  const int* pos        = (const int*)d_in[1];   // harness passes integers as int32
  const float* Wqa      = (const float*)d_in[2];
  const float* g_qa     = (const float*)d_in[3];
  const float* Wqb      = (const float*)d_in[4];
  const float* Wkva     = (const float*)d_in[5];
  const float* g_kva    = (const float*)d_in[6];
  const float* Wkvb     = (const float*)d_in[7];
  const float* Wo       = (const float*)d_in[8];
  const float* cosT     = (const float*)d_in[9];
  const float* sinT     = (const float*)d_in[10];
  float* out            = (float*)d_out;

  // ---- workspace layout ----
  size_t off = 0;
  char* wsp = (char*)d_ws;
  auto alloc = [&](size_t n) { void* p = wsp + off; off += (n + 255) & ~(size_t)255; return p; };
  bf16*  Wqa_t  = (bf16*) alloc((size_t)QR * HD * 2);      // contiguous with
  bf16*  Wkva_t = (bf16*) alloc((size_t)768 * HD * 2);     //  ... Wqa_t (2304-row Bt)
  bf16*  Wqb_t  = (bf16*) alloc((size_t)NQB * QR * 2);
  bf16*  Wkvb_t = (bf16*) alloc((size_t)NKVB * KVR * 2);
  bf16*  Wo_t   = (bf16*) alloc((size_t)HD * HD * 2);
  bf16*  x_bf   = (bf16*) alloc((size_t)NTOK * HD * 2);
  bf16*  q_bhsd = (bf16*) alloc((size_t)B_ * NH * S_ * DQK * 2);
  bf16*  k_bhsd = (bf16*) alloc((size_t)B_ * NH * S_ * DQK * 2);
  bf16*  v_t    = (bf16*) alloc((size_t)B_ * NH * DV * S_ * 2);
  bf16*  att    = (bf16*) alloc((size_t)NTOK * 2048 * 2);
  char*  T      = (char*) alloc((size_t)37748736);         // 36 MB transient
  bf16*  xa  = (bf16*)T;                        // [NTOK][2304] = 18.87 MB
  bf16*  q_n = (bf16*)(T + 18874368);           // [NTOK][1536] = 12.6 MB
  bf16*  kv_l = (bf16*)(T + 18874368 + 12582912); // [NTOK][512] = 4.2 MB
  if (ws_size < off) return;

  // ---- transposes + x cvt in one launch (15360 + 8192 blocks) ----
  TransArgs ta = {Wqa, Wkva, Wqb, Wkvb, Wo, x,
                  Wqa_t, Wkva_t, Wqb_t, Wkvb_t, Wo_t, x_bf};
  transpose_all<<<23552, 256, 0, stream>>>(ta);
  // ---- combined first-stage GEMM (gemm8p, N padded to 2304): xa = x_bf @ W ---
  gemm8p_c<bf16><<<dim3(NQKVAP / 256, NTOK / 256), 512, 0, stream>>>(x_bf, Wqa_t, xa, NQKVAP, HD);
  // ---- merged norms + rope prep ----
  norm_prep<<<NTOK, 256, 0, stream>>>(xa, g_qa, g_kva, pos, cosT, sinT, q_n, kv_l, k_bhsd);
  // ---- merged Q + KV projection GEMMs (448 blocks, one launch) ----
  gemm8p_qkv<<<448, 512, 0, stream>>>(q_n, Wqb_t, kv_l, Wkvb_t, pos, cosT, sinT,
                                      q_bhsd, k_bhsd, v_t);
  // ---- attention + output projection ----
  flash4<<<512, 512, 0, stream>>>(q_bhsd, k_bhsd, v_t, att);
  gemm_bf16<float><<<dim3(HD / 128, NTOK / 128), 256, 0, stream>>>(att, Wo_t, out, NTOK, HD, HD);
}

// Round 17
// 290.530 us; speedup vs baseline: 1.1045x; 1.0215x over previous
//
#include <hip/hip_runtime.h>
#include <hip/hip_bf16.h>

typedef __bf16 bf16;
typedef __bf16 bf16x8 __attribute__((ext_vector_type(8)));
typedef __bf16 bf16x4 __attribute__((ext_vector_type(4)));
typedef float f32x4 __attribute__((ext_vector_type(4)));

#define B_    2
#define S_    2048
#define HD    2048
#define NH    16
#define DQK   192
#define DV    128
#define QR    1536
#define KVR   512
#define NTOK  4096
#define NKVB  4096   /* N_HEADS*(D_NOPE+D_V) */
#define NQB   3072   /* N_HEADS*D_QK */
#define NQKVAP 2304  /* QR + 768 (padded kv_a, 9*256) */

#define EXP2F(x) __builtin_amdgcn_exp2f(x)

static __device__ __forceinline__ void gload16(const void* g, void* l) {
  __builtin_amdgcn_global_load_lds(
      (const __attribute__((address_space(1))) void*)g,
      (__attribute__((address_space(3))) void*)l, 16, 0, 0);
}

// ---------------- prep A: x f32->bf16 + Wqa/Wkva transposes (pre-xa-GEMM) -----
struct PrepArgs {
  const float *x, *Wqa, *Wkva;
  bf16 *xb, *Wqa_t, *Wkva_t;
};
__global__ __launch_bounds__(256) void prep_a(PrepArgs a) {
  int bid = blockIdx.x;
  if (bid < 8192) {                   // x f32 -> bf16
    long i = ((long)bid * 256 + threadIdx.x) * 4;
    float4 v = *(const float4*)(a.x + i);
    bf16x4 o = {(bf16)v.x, (bf16)v.y, (bf16)v.z, (bf16)v.w};
    *(bf16x4*)(a.xb + i) = o;
    return;
  }
  __shared__ float tile[32][33];
  int g = bid - 8192;                 // [0, 4608)
  int seg = (g < 3072) ? 0 : 1;
  int rel = (seg == 0) ? g : g - 3072;
  const float* in = seg == 0 ? a.Wqa : a.Wkva;
  bf16* out       = seg == 0 ? a.Wqa_t : a.Wkva_t;
  int C   = seg == 0 ? 1536 : 576;
  int Np  = seg == 0 ? 1536 : 768;
  int nbx = seg == 0 ? 48 : 24;
  const int R = 2048;
  int c0 = (rel % nbx) * 32;
  int r0 = (rel / nbx) * 32;
  int tx = threadIdx.x & 31, ty = threadIdx.x >> 5;
#pragma unroll
  for (int i = 0; i < 4; ++i) {
    int r = r0 + ty + i * 8, c = c0 + tx;
    tile[ty + i * 8][tx] = (c < C) ? in[(long)r * C + c] : 0.f;
  }
  __syncthreads();
#pragma unroll
  for (int i = 0; i < 4; ++i) {
    int oc = c0 + ty + i * 8;
    if (oc < Np) out[(long)oc * R + r0 + tx] = (bf16)tile[tx][ty + i * 8];
  }
}

// ============ shared GEMM core: 128x128 tile, BK=64, XOR chunk swizzle ========
#define GEMM_CORE(A, Bt, K)                                                    \
  __shared__ bf16 As[128 * 64];                                                \
  __shared__ bf16 Bs[128 * 64];                                                \
  const int t = threadIdx.x;                                                   \
  const int l = t & 63;                                                        \
  const int w = t >> 6;                                                        \
  const int m0 = blockIdx.y * 128;                                             \
  const int n0 = blockIdx.x * 128;                                             \
  const int wr = (w >> 1) * 64;                                                \
  const int wc = (w & 1) * 64;                                                 \
  const int lr = l & 15;                                                       \
  const int lg = l >> 4;                                                       \
  f32x4 acc[4][4] = {};                                                        \
  for (int k0 = 0; k0 < (K); k0 += 64) {                                       \
    __syncthreads();                                                           \
    _Pragma("unroll")                                                          \
    for (int j = 0; j < 4; ++j) {                                              \
      int s = j * 256 + t;                                                     \
      int row = s >> 3, sc = s & 7;                                            \
      int c = sc ^ (row & 7);                                                  \
      gload16((A) + (long)(m0 + row) * (K) + k0 + c * 8,                       \
              As + (j * 256 + w * 64) * 8);                                    \
      gload16((Bt) + (long)(n0 + row) * (K) + k0 + c * 8,                      \
              Bs + (j * 256 + w * 64) * 8);                                    \
    }                                                                          \
    __syncthreads();                                                           \
    _Pragma("unroll")                                                          \
    for (int kh = 0; kh < 2; ++kh) {                                           \
      bf16x8 af[4], bfr[4];                                                    \
      _Pragma("unroll")                                                        \
      for (int m = 0; m < 4; ++m) {                                            \
        int row = wr + m * 16 + lr;                                            \
        af[m] = *(const bf16x8*)(As + row * 64 + (((kh * 4 + lg) ^ (row & 7)) << 3)); \
      }                                                                        \
      _Pragma("unroll")                                                        \
      for (int n = 0; n < 4; ++n) {                                            \
        int row = wc + n * 16 + lr;                                            \
        bfr[n] = *(const bf16x8*)(Bs + row * 64 + (((kh * 4 + lg) ^ (row & 7)) << 3)); \
      }                                                                        \
      _Pragma("unroll")                                                        \
      for (int m = 0; m < 4; ++m)                                              \
        _Pragma("unroll")                                                      \
        for (int n = 0; n < 4; ++n)                                            \
          acc[m][n] = __builtin_amdgcn_mfma_f32_16x16x32_bf16(af[m], bfr[n], acc[m][n], 0, 0, 0); \
    }                                                                          \
  }

// ---------------- generic GEMM: C[M][N] = A @ Bt^T ----------------------------
template <typename CT>
__global__ __launch_bounds__(256) void gemm_bf16(const bf16* __restrict__ A,
                                                 const bf16* __restrict__ Bt,
                                                 CT* __restrict__ C,
                                                 int M, int N, int K) {
  GEMM_CORE(A, Bt, K)
#pragma unroll
  for (int m = 0; m < 4; ++m)
#pragma unroll
    for (int n = 0; n < 4; ++n)
#pragma unroll
      for (int v = 0; v < 4; ++v) {
        int row = m0 + wr + m * 16 + lg * 4 + v;
        int col = n0 + wc + n * 16 + lr;
        C[(long)row * N + col] = (CT)acc[m][n][v];
      }
}

// ============ gemm8p body: 256x256 tile, BK=64, 8 waves, 2-dbuf, counted vmcnt
// Requires __shared__ bf16 As_[2][256*64], Bs_[2][256*64] in enclosing scope.
#define G8P_BODY(A, Bt, K, M0, N0)                                             \
  const int t = threadIdx.x;                                                   \
  const int w = t >> 6, l = t & 63;                                            \
  const int lr = l & 15, lg = l >> 4;                                          \
  const int wm = w >> 2, wn = w & 3;                                           \
  const int m0 = (M0), n0 = (N0);                                              \
  const int NT = (K) >> 6;                                                     \
  const int tr = t >> 3, sc = t & 7;                                           \
  f32x4 acc[8][4] = {};                                                        \
  auto stg = [&](int kt, int j) {                                              \
    int jj = j & 3;                                                            \
    int row = jj * 64 + tr;                                                    \
    int c = sc ^ (row & 7);                                                    \
    const bf16* src = (j < 4)                                                  \
        ? (A)  + (long)(m0 + row) * (K) + kt * 64 + c * 8                      \
        : (Bt) + (long)(n0 + row) * (K) + kt * 64 + c * 8;                     \
    bf16* dst = ((j < 4) ? As_[kt & 1] : Bs_[kt & 1]) + (jj * 512 + w * 64) * 8; \
    gload16(src, dst);                                                         \
  };                                                                           \
  _Pragma("unroll") for (int j = 0; j < 8; ++j) stg(0, j);                     \
  _Pragma("unroll") for (int j = 0; j < 8; ++j) stg(1, j);                     \
  for (int kt = 0; kt < NT; ++kt) {                                            \
    const bf16* Ab = As_[kt & 1];                                              \
    const bf16* Bb = Bs_[kt & 1];                                              \
    if (kt == NT - 1) { asm volatile("s_waitcnt vmcnt(0)" ::: "memory"); }     \
    else              { asm volatile("s_waitcnt vmcnt(8)" ::: "memory"); }     \
    __builtin_amdgcn_s_barrier();                                              \
    asm volatile("" ::: "memory");                                             \
    bf16x8 af[8][2], bfr[4][2];                                                \
    _Pragma("unroll")                                                          \
    for (int mi = 0; mi < 8; ++mi) {                                           \
      int row = wm * 128 + mi * 16 + lr;                                       \
      _Pragma("unroll")                                                        \
      for (int kh = 0; kh < 2; ++kh)                                           \
        af[mi][kh] = *(const bf16x8*)(Ab + row * 64 + (((kh * 4 + lg) ^ (row & 7)) << 3)); \
    }                                                                          \
    _Pragma("unroll")                                                          \
    for (int ni = 0; ni < 4; ++ni) {                                           \
      int row = wn * 64 + ni * 16 + lr;                                        \
      _Pragma("unroll")                                                        \
      for (int kh = 0; kh < 2; ++kh)                                           \
        bfr[ni][kh] = *(const bf16x8*)(Bb + row * 64 + (((kh * 4 + lg) ^ (row & 7)) << 3)); \
    }                                                                          \
    asm volatile("s_waitcnt lgkmcnt(0)" ::: "memory");                         \
    __builtin_amdgcn_sched_barrier(0);                                         \
    __builtin_amdgcn_s_setprio(1);                                             \
    _Pragma("unroll")                                                          \
    for (int mi = 0; mi < 8; ++mi)                                             \
      _Pragma("unroll")                                                        \
      for (int kh = 0; kh < 2; ++kh)                                           \
        acc[mi][0] = __builtin_amdgcn_mfma_f32_16x16x32_bf16(af[mi][kh], bfr[0][kh], acc[mi][0], 0, 0, 0); \
    __builtin_amdgcn_s_setprio(0);                                             \
    __builtin_amdgcn_s_barrier();  /* all waves' ds_reads done: dbufs free */  \
    asm volatile("" ::: "memory");                                             \
    bool more = (kt + 2) < NT;                                                 \
    if (more) { stg(kt + 2, 0); stg(kt + 2, 1); stg(kt + 2, 2); }              \
    __builtin_amdgcn_s_setprio(1);                                             \
    _Pragma("unroll")                                                          \
    for (int mi = 0; mi < 8; ++mi)                                             \
      _Pragma("unroll")                                                        \
      for (int kh = 0; kh < 2; ++kh)                                           \
        acc[mi][1] = __builtin_amdgcn_mfma_f32_16x16x32_bf16(af[mi][kh], bfr[1][kh], acc[mi][1], 0, 0, 0); \
    __builtin_amdgcn_s_setprio(0);                                             \
    if (more) { stg(kt + 2, 3); stg(kt + 2, 4); stg(kt + 2, 5); }              \
    __builtin_amdgcn_s_setprio(1);                                             \
    _Pragma("unroll")                                                          \
    for (int mi = 0; mi < 8; ++mi)                                             \
      _Pragma("unroll")                                                        \
      for (int kh = 0; kh < 2; ++kh)                                           \
        acc[mi][2] = __builtin_amdgcn_mfma_f32_16x16x32_bf16(af[mi][kh], bfr[2][kh], acc[mi][2], 0, 0, 0); \
    __builtin_amdgcn_s_setprio(0);                                             \
    if (more) { stg(kt + 2, 6); stg(kt + 2, 7); }                              \
    __builtin_amdgcn_s_setprio(1);                                             \
    _Pragma("unroll")                                                          \
    for (int mi = 0; mi < 8; ++mi)                                             \
      _Pragma("unroll")                                                        \
      for (int kh = 0; kh < 2; ++kh)                                           \
        acc[mi][3] = __builtin_amdgcn_mfma_f32_16x16x32_bf16(af[mi][kh], bfr[3][kh], acc[mi][3], 0, 0, 0); \
    __builtin_amdgcn_s_setprio(0);                                             \
  }

// ---------------- merged xa gemm8p (blocks 0..143) + big transposes (rest) ----
// blocks [0,144): xa = x_bf @ [Wqa|Wkva]^T, 256^2 tiles, 9x16 grid flattened.
// blocks [144,5520): Wqb/Wkvb/Wo f32 transposes, two 32x32 tiles per block
// (half = t>>8), backfilling CUs the 144-block GEMM leaves idle.
struct XtArgs {
  const bf16 *x_bf, *Wt;              // Wt = Wqa_t (2304-row concat)
  bf16 *xa;
  const float *Wqb, *Wkvb, *Wo;
  bf16 *Wqb_t, *Wkvb_t, *Wo_t;
};
__global__ __launch_bounds__(512) void gemm8p_xt(XtArgs a) {
  __shared__ bf16 As_[2][256 * 64];
  __shared__ bf16 Bs_[2][256 * 64];
  __shared__ float ttile[2][32][33];
  int bid = blockIdx.x;
  if (bid >= 144) {
    int half = threadIdx.x >> 8;      // 0 or 1
    int tt = threadIdx.x & 255;
    int g = (bid - 144) * 2 + half;   // [0, 10752)
    int seg, rel;
    if      (g < 4608) { seg = 0; rel = g; }          // Wqb
    else if (g < 6656) { seg = 1; rel = g - 4608; }   // Wkvb
    else               { seg = 2; rel = g - 6656; }   // Wo
    const float* in = seg == 0 ? a.Wqb : seg == 1 ? a.Wkvb : a.Wo;
    bf16* out       = seg == 0 ? a.Wqb_t : seg == 1 ? a.Wkvb_t : a.Wo_t;
    int R   = seg == 0 ? 1536 : seg == 1 ? 512 : 2048;
    int C   = seg == 0 ? 3072 : seg == 1 ? 4096 : 2048;
    int nbx = seg == 0 ? 96 : seg == 1 ? 128 : 64;
    int c0 = (rel % nbx) * 32;
    int r0 = (rel / nbx) * 32;
    int tx = tt & 31, ty = tt >> 5;
#pragma unroll
    for (int i = 0; i < 4; ++i) {
      int r = r0 + ty + i * 8, c = c0 + tx;
      ttile[half][ty + i * 8][tx] = in[(long)r * C + c];
    }
    __syncthreads();
#pragma unroll
    for (int i = 0; i < 4; ++i) {
      int oc = c0 + ty + i * 8;
      out[(long)oc * R + r0 + tx] = (bf16)ttile[half][tx][ty + i * 8];
    }
    return;
  }
  // ---- xa GEMM path: grid 9(N) x 16(M) flattened ----
  {
    int bx = bid % 9, by = bid / 9;
    G8P_BODY(a.x_bf, a.Wt, HD, by * 256, bx * 256)
#pragma unroll
    for (int mi = 0; mi < 8; ++mi)
#pragma unroll
      for (int ni = 0; ni < 4; ++ni)
#pragma unroll
        for (int v = 0; v < 4; ++v) {
          int row = m0 + wm * 128 + mi * 16 + lg * 4 + v;
          int col = n0 + wn * 64 + ni * 16 + lr;
          a.xa[(long)row * NQKVAP + col] = (bf16)acc[mi][ni][v];
        }
  }
}

// ---------------- merged qf+kvb gemm8p launch (448 blocks, uniform branch) ----
__global__ __launch_bounds__(512) void gemm8p_qkv(
    const bf16* __restrict__ q_n,  const bf16* __restrict__ Wqb_t,
    const bf16* __restrict__ kv_l, const bf16* __restrict__ Wkvb_t,
    const int* __restrict__ pos,
    const float* __restrict__ cosT, const float* __restrict__ sinT,
    bf16* __restrict__ q_bhsd, bf16* __restrict__ k_bhsd,
    bf16* __restrict__ v_t) {
  __shared__ bf16 As_[2][256 * 64];
  __shared__ bf16 Bs_[2][256 * 64];
  int bid = blockIdx.x;
  if (bid < 192) {
    // ---- q_f path: M=4096, N=3072, K=1536; grid 12 x 16 flattened ----
    const float SCALE = 0.07216878364870323f * 1.4426950408889634f;
    int bx = bid % 12, by = bid / 12;
    G8P_BODY(q_n, Wqb_t, QR, by * 256, bx * 256)
    int c0 = n0 + wn * 64;
    int h = c0 / 192;
    int part = c0 - h * 192;          // 0, 64, or 128 (wave-uniform)
#pragma unroll
    for (int mi = 0; mi < 8; ++mi)
#pragma unroll
      for (int v = 0; v < 4; ++v) {
        int row = m0 + wm * 128 + mi * 16 + lg * 4 + v;
        int b = row >> 11, s = row & (S_ - 1);
        long base = ((long)(b * NH + h) * S_ + s) * DQK;
        if (part < 128) {
#pragma unroll
          for (int ni = 0; ni < 4; ++ni)
            q_bhsd[base + part + ni * 16 + lr] = (bf16)(acc[mi][ni][v] * SCALE);
        } else {
          int p = pos[s] & (S_ - 1);
          float c_lo = cosT[p * 32 + lr],      s_lo = sinT[p * 32 + lr];
          float c_hi = cosT[p * 32 + 16 + lr], s_hi = sinT[p * 32 + 16 + lr];
          float o0 = acc[mi][0][v] * c_lo - acc[mi][2][v] * s_lo;
          float o1 = acc[mi][1][v] * c_hi - acc[mi][3][v] * s_hi;
          float o2 = acc[mi][0][v] * s_lo + acc[mi][2][v] * c_lo;
          float o3 = acc[mi][1][v] * s_hi + acc[mi][3][v] * c_hi;
          q_bhsd[base + 128 + lr] = (bf16)(o0 * SCALE);
          q_bhsd[base + 144 + lr] = (bf16)(o1 * SCALE);
          q_bhsd[base + 160 + lr] = (bf16)(o2 * SCALE);
          q_bhsd[base + 176 + lr] = (bf16)(o3 * SCALE);
        }
      }
  } else {
    // ---- kv_b path: M=4096, N=4096, K=512; grid 16 x 16 flattened ----
    int rel = bid - 192;
    int bx = rel & 15, by = rel >> 4;
    G8P_BODY(kv_l, Wkvb_t, KVR, by * 256, bx * 256)
    int c0 = n0 + wn * 64;
    int h = c0 >> 8;
    int dbase = c0 & 64;
    bool vpart = (c0 >> 7) & 1;
    if (!vpart) {
#pragma unroll
      for (int mi = 0; mi < 8; ++mi)
#pragma unroll
        for (int v = 0; v < 4; ++v) {
          int row = m0 + wm * 128 + mi * 16 + lg * 4 + v;
          int b = row >> 11, s = row & (S_ - 1);
          long base = ((long)(b * NH + h) * S_ + s) * DQK + dbase;
#pragma unroll
          for (int ni = 0; ni < 4; ++ni)
            k_bhsd[base + ni * 16 + lr] = (bf16)acc[mi][ni][v];
        }
    } else {
#pragma unroll
      for (int mi = 0; mi < 8; ++mi) {
        int row0 = m0 + wm * 128 + mi * 16 + lg * 4;
        int b = row0 >> 11, s = row0 & (S_ - 1);
#pragma unroll
        for (int ni = 0; ni < 4; ++ni) {
          int d = dbase + ni * 16 + lr;
          bf16x4 o = {(bf16)acc[mi][ni][0], (bf16)acc[mi][ni][1],
                      (bf16)acc[mi][ni][2], (bf16)acc[mi][ni][3]};
          *(bf16x4*)(v_t + ((long)(b * NH + h) * DV + d) * S_ + s) = o;
        }
      }
    }
  }
}

// ---------------- merged norm+prep: waves 0-2 q-RMSNorm, wave 3 kv+rope -------
__global__ __launch_bounds__(256) void norm_prep(const bf16* __restrict__ xa,   // [NTOK][2304]
                                                 const float* __restrict__ g_qa,
                                                 const float* __restrict__ g_kva,
                                                 const int* __restrict__ pos,
                                                 const float* __restrict__ cosT,
                                                 const float* __restrict__ sinT,
                                                 bf16* __restrict__ q_n,       // [NTOK][1536]
                                                 bf16* __restrict__ kv_l,      // [NTOK][512]
                                                 bf16* __restrict__ k_bhsd) {  // [B][H][S][192]
  int row = blockIdx.x;
  int t = threadIdx.x;
  int b = row >> 11, s = row & (S_ - 1);
  const bf16* xr = xa + (long)row * NQKVAP;
  __shared__ float red[3];
  __shared__ bf16 rope_s[64];
  float vf[8];
  if (t < 192) {
    bf16x8 vv = *(const bf16x8*)(xr + t * 8);
    float ss = 0.f;
#pragma unroll
    for (int e = 0; e < 8; ++e) { vf[e] = (float)vv[e]; ss += vf[e] * vf[e]; }
#pragma unroll
    for (int m = 1; m < 64; m <<= 1) ss += __shfl_xor(ss, m);
    if ((t & 63) == 0) red[t >> 6] = ss;
  } else {
    int tt = t - 192;
    const bf16* xl = xr + QR;
    bf16x8 vv = *(const bf16x8*)(xl + tt * 8);
    float ss = 0.f;
#pragma unroll
    for (int e = 0; e < 8; ++e) { vf[e] = (float)vv[e]; ss += vf[e] * vf[e]; }
#pragma unroll
    for (int m = 1; m < 64; m <<= 1) ss += __shfl_xor(ss, m);
    float rs = rsqrtf(ss / KVR + 1e-5f);
    bf16x8 o;
#pragma unroll
    for (int e = 0; e < 8; ++e) o[e] = (bf16)(vf[e] * rs * g_kva[tt * 8 + e]);
    *(bf16x8*)(kv_l + (long)row * KVR + tt * 8) = o;
    if (tt < 32) {
      int p = pos[s] & (S_ - 1);
      float c = cosT[p * 32 + tt], sn = sinT[p * 32 + tt];
      float x0 = (float)xl[512 + tt], x1 = (float)xl[544 + tt];
      rope_s[tt] = (bf16)(x0 * c - x1 * sn);
      rope_s[32 + tt] = (bf16)(x0 * sn + x1 * c);
    }
  }
  __syncthreads();
  if (t < 192) {
    float ss = red[0] + red[1] + red[2];
    float rs = rsqrtf(ss / QR + 1e-5f);
    bf16x8 o;
#pragma unroll
    for (int e = 0; e < 8; ++e) o[e] = (bf16)(vf[e] * rs * g_qa[t * 8 + e]);
    *(bf16x8*)(q_n + (long)row * QR + t * 8) = o;
  } else {
    int tt = t - 192;
    bf16x8 rv = *(const bf16x8*)&rope_s[(tt & 7) * 8];
    long base0 = ((long)(b * NH + (tt >> 3)) * S_ + s) * DQK + 128 + (tt & 7) * 8;
    long base1 = ((long)(b * NH + 8 + (tt >> 3)) * S_ + s) * DQK + 128 + (tt & 7) * 8;
    *(bf16x8*)(k_bhsd + base0) = rv;
    *(bf16x8*)(k_bhsd + base1) = rv;
  }
}

// ---------------- flash v4 (proven 91us): 8 waves x 16 q-rows, QBLK=128 -------
#define KVB  64
#define DVP  144
__global__ __launch_bounds__(512) void flash4(const bf16* __restrict__ q_bhsd,
                                              const bf16* __restrict__ k_bhsd,
                                              const bf16* __restrict__ v_t,
                                              bf16* __restrict__ att) {  // [NTOK][2048]
  __shared__ bf16 Ks[KVB * DQK];      // 24 KB, swizzled 16B chunks
  __shared__ bf16 Vs[DVP * KVB];      // 18 KB, rows 0-127 staged, 128-143 const
  __shared__ bf16 Ps[8][16 * 72];     // 18 KB, per-wave P, padded to 72
  int bid = blockIdx.x;
  int bh = bid & 31;                  // head-of-batch: fixes XCD = bh%8
  int qt = 15 - (bid >> 5);           // heaviest (most k-tiles) first
  int b = bh >> 4, h = bh & 15;
  int q0 = qt * 128;
  int t = threadIdx.x;
  int w = t >> 6, l = t & 63;
  int lr = l & 15, lg = l >> 4;
  int qw = q0 + w * 16;               // this wave's first q row

  const bf16* Qb = q_bhsd + (long)bh * S_ * DQK;
  const bf16* Kb = k_bhsd + (long)bh * S_ * DQK;
  const bf16* Vb = v_t + (long)bh * DV * S_;

  // init ones/zero rows of Vs (persist across tiles; staging never touches them)
  if (t < 128) {
    int rr = 128 + (t >> 3), cc = (t & 7) * 8;
    bf16 val = (bf16)((rr == 128) ? 1.0f : 0.0f);
    bf16x8 vvv = {val, val, val, val, val, val, val, val};
    *(bf16x8*)(Vs + rr * KVB + cc) = vvv;
  }

  bf16x8 qf[6];
#pragma unroll
  for (int t6 = 0; t6 < 6; ++t6)
    qf[t6] = *(const bf16x8*)(Qb + (long)(qw + lr) * DQK + t6 * 32 + lg * 8);

  f32x4 oacc[9] = {};                 // [0..7] output, [8] = l (ones-row)
  float mrow[4] = {-1e30f, -1e30f, -1e30f, -1e30f};
  const int lr7 = lr & 7;

  int nkt = 2 * qt + 2;
  for (int kt = 0; kt < nkt; ++kt) {
    int k0 = kt * KVB;
    __syncthreads();
    // stage K: 1536 chunks (3 x 512); slot s holds global chunk (r, c^(r&7))
#pragma unroll
    for (int j = 0; j < 3; ++j) {
      int s = j * 512 + t;
      int r = s / 24, c1 = s - r * 24;
      int c = c1 ^ (r & 7);
      gload16(Kb + (long)(k0 + r) * DQK + c * 8, Ks + (j * 512 + w * 64) * 8);
    }
    // stage V: 1024 chunks (2 x 512), rows 0..127 only
#pragma unroll
    for (int j = 0; j < 2; ++j) {
      int s = j * 512 + t;
      int d = s >> 3, c1 = s & 7;
      int c = c1 ^ (d & 7);
      gload16(Vb + (long)d * S_ + k0 + c * 8, Vs + (j * 512 + w * 64) * 8);
    }
    __syncthreads();
    if (k0 > qw + 15) continue;       // fully masked for this wave

    // ---- QK^T: sacc[n] = scores[q=lg*4+v][k=n*16+lr] (log2-domain) ----
    f32x4 sacc[4] = {};
#pragma unroll
    for (int n = 0; n < 4; ++n) {
      int rk = n * 16 + lr;
#pragma unroll
      for (int t6 = 0; t6 < 6; ++t6) {
        bf16x8 kf = *(const bf16x8*)(Ks + rk * DQK + (((t6 * 4 + lg) ^ lr7) << 3));
        sacc[n] = __builtin_amdgcn_mfma_f32_16x16x32_bf16(qf[t6], kf, sacc[n], 0, 0, 0);
      }
    }
    // ---- causal mask (diagonal tiles only) ----
    if (k0 + KVB - 1 > qw) {
#pragma unroll
      for (int n = 0; n < 4; ++n)
#pragma unroll
        for (int v = 0; v < 4; ++v) {
          int r = lg * 4 + v, c = n * 16 + lr;
          if (k0 + c > qw + r) sacc[n][v] = -1e30f;
        }
    }
    // ---- tile row-max ----
    float mv[4];
#pragma unroll
    for (int v = 0; v < 4; ++v) {
      mv[v] = fmaxf(fmaxf(sacc[0][v], sacc[1][v]), fmaxf(sacc[2][v], sacc[3][v]));
#pragma unroll
      for (int msk = 1; msk < 16; msk <<= 1) mv[v] = fmaxf(mv[v], __shfl_xor(mv[v], msk));
    }
    // ---- defer-max: rescale only if some row max grew by > 8 (log2) ----
    bool grow = (mv[0] > mrow[0] + 8.f) | (mv[1] > mrow[1] + 8.f) |
                (mv[2] > mrow[2] + 8.f) | (mv[3] > mrow[3] + 8.f);
    if (__any(grow)) {
      float corr[4];
#pragma unroll
      for (int v = 0; v < 4; ++v) {
        float mt = fmaxf(mrow[v], mv[v]);
        corr[v] = EXP2F(mrow[v] - mt);
        mrow[v] = mt;
      }
#pragma unroll
      for (int dn = 0; dn < 9; ++dn)
#pragma unroll
        for (int v = 0; v < 4; ++v) oacc[dn][v] *= corr[v];
    }
    // ---- P = exp2(s - mrow); P -> LDS (per-wave, padded) ----
#pragma unroll
    for (int v = 0; v < 4; ++v)
#pragma unroll
      for (int n = 0; n < 4; ++n)
        Ps[w][(lg * 4 + v) * 72 + n * 16 + lr] = (bf16)EXP2F(sacc[n][v] - mrow[v]);
    // ---- PV: oacc[dn] += P[16x64] @ V^T; dn=8 hits the ones-row => l ----
#pragma unroll
    for (int kc = 0; kc < 2; ++kc) {
      bf16x8 pf = *(const bf16x8*)(Ps[w] + lr * 72 + kc * 32 + lg * 8);
#pragma unroll
      for (int dn = 0; dn < 9; ++dn) {
        int d = dn * 16 + lr;
        bf16x8 vf = *(const bf16x8*)(Vs + d * KVB + (((kc * 4 + lg) ^ lr7) << 3));
        oacc[dn] = __builtin_amdgcn_mfma_f32_16x16x32_bf16(pf, vf, oacc[dn], 0, 0, 0);
      }
    }
  }
  // ---- epilogue: l lives in column d=128 (lanes lr==0); broadcast + divide ----
  float rl[4];
#pragma unroll
  for (int v = 0; v < 4; ++v) {
    float lv = __shfl(oacc[8][v], lg * 16);
    rl[v] = 1.0f / lv;
  }
#pragma unroll
  for (int dn = 0; dn < 8; ++dn)
#pragma unroll
    for (int v = 0; v < 4; ++v) {
      int r = lg * 4 + v;
      float o = oacc[dn][v] * rl[v];
      att[((long)(b * S_ + qw + r)) * 2048 + h * 128 + dn * 16 + lr] = (bf16)o;
    }
}

extern "C" void kernel_launch(void* const* d_in, const int* in_sizes, int n_in,
                              void* d_out, int out_size, void* d_ws, size_t ws_size,
                              hipStream_t stream) {
  const float* x        = (const float*)d_in[0];
  const int* pos        = (const int*)d_in[1];   // harness passes integers as int32
  const float* Wqa      = (const float*)d_in[2];
  const float* g_qa     = (const float*)d_in[3];
  const float* Wqb      = (const float*)d_in[4];
  const float* Wkva     = (const float*)d_in[5];
  const float* g_kva    = (const float*)d_in[6];
  const float* Wkvb     = (const float*)d_in[7];
  const float* Wo       = (const float*)d_in[8];
  const float* cosT     = (const float*)d_in[9];
  const float* sinT     = (const float*)d_in[10];
  float* out            = (float*)d_out;

  // ---- workspace layout ----
  size_t off = 0;
  char* wsp = (char*)d_ws;
  auto alloc = [&](size_t n) { void* p = wsp + off; off += (n + 255) & ~(size_t)255; return p; };
  bf16*  Wqa_t  = (bf16*) alloc((size_t)QR * HD * 2);      // contiguous with
  bf16*  Wkva_t = (bf16*) alloc((size_t)768 * HD * 2);     //  ... Wqa_t (2304-row Bt)
  bf16*  Wqb_t  = (bf16*) alloc((size_t)NQB * QR * 2);
  bf16*  Wkvb_t = (bf16*) alloc((size_t)NKVB * KVR * 2);
  bf16*  Wo_t   = (bf16*) alloc((size_t)HD * HD * 2);
  bf16*  x_bf   = (bf16*) alloc((size_t)NTOK * HD * 2);
  bf16*  q_bhsd = (bf16*) alloc((size_t)B_ * NH * S_ * DQK * 2);
  bf16*  k_bhsd = (bf16*) alloc((size_t)B_ * NH * S_ * DQK * 2);
  bf16*  v_t    = (bf16*) alloc((size_t)B_ * NH * DV * S_ * 2);
  bf16*  att    = (bf16*) alloc((size_t)NTOK * 2048 * 2);
  char*  T      = (char*) alloc((size_t)37748736);         // 36 MB transient
  bf16*  xa  = (bf16*)T;                        // [NTOK][2304] = 18.87 MB
  bf16*  q_n = (bf16*)(T + 18874368);           // [NTOK][1536] = 12.6 MB
  bf16*  kv_l = (bf16*)(T + 18874368 + 12582912); // [NTOK][512] = 4.2 MB
  if (ws_size < off) return;

  // ---- prep A: x cvt + Wqa/Wkva transposes (xa-GEMM inputs) ----
  PrepArgs pa = {x, Wqa, Wkva, x_bf, Wqa_t, Wkva_t};
  prep_a<<<12800, 256, 0, stream>>>(pa);
  // ---- xa GEMM (144 blocks) co-scheduled with Wqb/Wkvb/Wo transposes ----
  XtArgs xt = {x_bf, Wqa_t, xa, Wqb, Wkvb, Wo, Wqb_t, Wkvb_t, Wo_t};
  gemm8p_xt<<<5520, 512, 0, stream>>>(xt);
  // ---- merged norms + rope prep ----
  norm_prep<<<NTOK, 256, 0, stream>>>(xa, g_qa, g_kva, pos, cosT, sinT, q_n, kv_l, k_bhsd);
  // ---- merged Q + KV projection GEMMs (448 blocks, one launch) ----
  gemm8p_qkv<<<448, 512, 0, stream>>>(q_n, Wqb_t, kv_l, Wkvb_t, pos, cosT, sinT,
                                      q_bhsd, k_bhsd, v_t);
  // ---- attention + output projection ----
  flash4<<<512, 512, 0, stream>>>(q_bhsd, k_bhsd, v_t, att);
  gemm_bf16<float><<<dim3(HD / 128, NTOK / 128), 256, 0, stream>>>(att, Wo_t, out, NTOK, HD, HD);
}